// Round 1
// baseline (6512.572 us; speedup 1.0000x reference)
//
#include <hip/hip_runtime.h>
#include <cstdint>
#include <cstddef>

#define NN     20000
#define NE     320000
#define NR     16
#define DIN    128
#define DH     512
#define DOUT   128
#define NT     50000
#define TILE   64
#define NTILES ((NE / TILE) + NR)

// ---------------- small precompute: fold attention vectors into weights ----------------
// alpha1[i][c], c = r*16 + s*8 + h : sum_o W1[r][i][h*64+o] * (s?ak1:aq1)[r][h][o]
__global__ void alpha1_kernel(const float* __restrict__ W1, const float* __restrict__ aq1,
                              const float* __restrict__ ak1, float* __restrict__ alpha1) {
    int i = blockIdx.x;            // 0..127
    int c = threadIdx.x;           // 0..255
    int r = c >> 4, s = (c >> 3) & 1, h = c & 7;
    const float* att = (s == 0 ? aq1 : ak1) + (r * 8 + h) * 64;
    const float* w = W1 + ((size_t)(r * DIN + i)) * DH + h * 64;
    float acc = 0.f;
    #pragma unroll 8
    for (int o = 0; o < 64; ++o) acc += w[o] * att[o];
    alpha1[i * 256 + c] = acc;
}

// alpha2[i][c], c = r*2 + s : sum_o W2[r][i][o] * (s?ak2:aq2)[r][o]
__global__ void alpha2_kernel(const float* __restrict__ W2, const float* __restrict__ aq2,
                              const float* __restrict__ ak2, float* __restrict__ alpha2) {
    int g = blockIdx.x * blockDim.x + threadIdx.x;
    if (g >= DH * 32) return;
    int i = g >> 5, c = g & 31;
    int r = c >> 1, s = c & 1;
    const float* att = (s == 0 ? aq2 : ak2) + r * DOUT;
    const float* w = W2 + ((size_t)(r * DH + i)) * DOUT;
    float acc = 0.f;
    #pragma unroll 8
    for (int o = 0; o < DOUT; ++o) acc += w[o] * att[o];
    alpha2[i * 32 + c] = acc;
}

// ---------------- counting sort of edges by relation ----------------
__global__ void count_kernel(const int* __restrict__ et, int* __restrict__ cnt) {
    __shared__ int bins[NR];
    int t = threadIdx.x;
    if (t < NR) bins[t] = 0;
    __syncthreads();
    int e = blockIdx.x * blockDim.x + t;
    if (e < NE) atomicAdd(&bins[et[e]], 1);
    __syncthreads();
    if (t < NR && bins[t] > 0) atomicAdd(&cnt[t], bins[t]);
}

__global__ void scan_kernel(const int* __restrict__ cnt, int* __restrict__ offs,
                            int* __restrict__ cursor) {
    if (threadIdx.x == 0) {
        int acc = 0;
        for (int r = 0; r < NR; ++r) { offs[r] = acc; cursor[r] = acc; acc += cnt[r]; }
        offs[NR] = acc;
    }
}

__global__ void tilemap_kernel(const int* __restrict__ offs, int* __restrict__ tile_r,
                               int* __restrict__ tile_s) {
    int t = blockIdx.x * blockDim.x + threadIdx.x;
    if (t >= NTILES) return;
    int acc = 0, rr = -1, ss = 0;
    for (int r = 0; r < NR; ++r) {
        int c = offs[r + 1] - offs[r];
        int nt = (c + TILE - 1) / TILE;
        if (t >= acc && t < acc + nt) { rr = r; ss = offs[r] + (t - acc) * TILE; }
        acc += nt;
    }
    tile_r[t] = rr; tile_s[t] = ss;
}

__global__ void bucket_kernel(const int* __restrict__ et, int* __restrict__ cursor,
                              int* __restrict__ border) {
    __shared__ int binc[NR], base[NR], rank[NR];
    int t = threadIdx.x;
    if (t < NR) { binc[t] = 0; rank[t] = 0; }
    __syncthreads();
    int e = blockIdx.x * blockDim.x + t;
    int r = (e < NE) ? et[e] : -1;
    if (r >= 0) atomicAdd(&binc[r], 1);
    __syncthreads();
    if (t < NR && binc[t] > 0) base[t] = atomicAdd(&cursor[t], binc[t]);
    __syncthreads();
    if (r >= 0) {
        int pos = base[r] + atomicAdd(&rank[r], 1);
        border[pos] = e;
    }
}

// ---------------- qk1 = x @ alpha1  ([N,128] @ [128,256]) ----------------
__global__ void qk1_kernel(const float* __restrict__ x, const float* __restrict__ alpha1,
                           float* __restrict__ qk1) {
    __shared__ float Xt[TILE][DIN + 1];
    int n0 = blockIdx.x * TILE;
    int tid = threadIdx.x;
    for (int idx = tid; idx < TILE * DIN; idx += 256) {
        int row = idx >> 7, i = idx & 127;
        int n = n0 + row;
        Xt[row][i] = (n < NN) ? x[(size_t)n * DIN + i] : 0.f;
    }
    __syncthreads();
    int to = tid >> 4, te = tid & 15;
    for (int c = 0; c < 2; ++c) {
        float acc[4][8] = {};
        const float* Wp = alpha1 + c * 128 + to * 8;
        for (int i = 0; i < DIN; ++i) {
            float4 w0 = *(const float4*)(Wp + (size_t)i * 256);
            float4 w1 = *(const float4*)(Wp + (size_t)i * 256 + 4);
            float w[8] = {w0.x, w0.y, w0.z, w0.w, w1.x, w1.y, w1.z, w1.w};
            #pragma unroll
            for (int a = 0; a < 4; ++a) {
                float xv = Xt[te * 4 + a][i];
                #pragma unroll
                for (int b = 0; b < 8; ++b) acc[a][b] += xv * w[b];
            }
        }
        #pragma unroll
        for (int a = 0; a < 4; ++a) {
            int n = n0 + te * 4 + a;
            if (n < NN) {
                float* op = qk1 + (size_t)n * 256 + c * 128 + to * 8;
                #pragma unroll
                for (int b = 0; b < 8; ++b) op[b] = acc[a][b];
            }
        }
    }
}

// ---------------- per-edge logits -> e = exp(leaky(l)), s1 = segment sum ----------------
__global__ void elogit1_kernel(const int* __restrict__ ei, const int* __restrict__ et,
                               const float* __restrict__ qk1, float* __restrict__ e1,
                               float* __restrict__ s1) {
    int e = blockIdx.x * blockDim.x + threadIdx.x;
    if (e >= NE) return;
    int src = ei[e], dst = ei[NE + e], r = et[e];
    const float* qp = qk1 + (size_t)dst * 256 + r * 16;
    const float* kp = qk1 + (size_t)src * 256 + r * 16 + 8;
    float ev[8];
    #pragma unroll
    for (int h = 0; h < 8; ++h) {
        float l = qp[h] + kp[h];
        l = l > 0.f ? l : 0.2f * l;
        ev[h] = __expf(l);
    }
    float* ep = e1 + (size_t)e * 8;
    #pragma unroll
    for (int h = 0; h < 8; ++h) ep[h] = ev[h];
    #pragma unroll
    for (int h = 0; h < 8; ++h) atomicAdd(&s1[dst * 8 + h], ev[h]);
}

// ---------------- layer1: relation-bucketed gather-GEMM + weighted atomic scatter ----------------
__global__ void l1_kernel(const float* __restrict__ x, const float* __restrict__ W1,
                          const int* __restrict__ ei, const int* __restrict__ border,
                          const int* __restrict__ tile_r, const int* __restrict__ tile_s,
                          const int* __restrict__ offs, const float* __restrict__ e1,
                          float* __restrict__ hacc) {
    int r = tile_r[blockIdx.x];
    if (r < 0) return;
    int start = tile_s[blockIdx.x];
    int cnt = offs[r + 1] - start; if (cnt > TILE) cnt = TILE;
    __shared__ float Xt[TILE][DIN + 1];
    __shared__ float ev[TILE][9];
    __shared__ int dstS[TILE], srcS[TILE];
    int tid = threadIdx.x;
    if (tid < TILE) {
        int sv = 0, dv = 0;
        if (tid < cnt) { int e = border[start + tid]; sv = ei[e]; dv = ei[NE + e]; }
        srcS[tid] = sv; dstS[tid] = dv;
    }
    for (int idx = tid; idx < TILE * 8; idx += 256) {
        int row = idx >> 3, h = idx & 7;
        float v = 0.f;
        if (row < cnt) { int e = border[start + row]; v = e1[(size_t)e * 8 + h]; }
        ev[row][h] = v;
    }
    __syncthreads();
    for (int idx = tid; idx < TILE * DIN; idx += 256) {
        int row = idx >> 7, i = idx & 127;
        Xt[row][i] = (row < cnt) ? x[(size_t)srcS[row] * DIN + i] : 0.f;
    }
    __syncthreads();
    int to = tid >> 4, te = tid & 15;
    const float* Wbase = W1 + (size_t)r * DIN * DH + to * 8;
    for (int c = 0; c < 4; ++c) {
        float acc[4][8] = {};
        const float* Wp = Wbase + c * 128;
        for (int i = 0; i < DIN; ++i) {
            const float* wr = Wp + (size_t)i * DH;
            float4 w0 = *(const float4*)(wr);
            float4 w1 = *(const float4*)(wr + 4);
            float w[8] = {w0.x, w0.y, w0.z, w0.w, w1.x, w1.y, w1.z, w1.w};
            #pragma unroll
            for (int a = 0; a < 4; ++a) {
                float xv = Xt[te * 4 + a][i];
                #pragma unroll
                for (int b = 0; b < 8; ++b) acc[a][b] += xv * w[b];
            }
        }
        int hb = c * 2 + (to >> 3);
        #pragma unroll
        for (int a = 0; a < 4; ++a) {
            int row = te * 4 + a;
            float wv = ev[row][hb];
            float* hp = hacc + (size_t)dstS[row] * DH + c * 128 + to * 8;
            #pragma unroll
            for (int b = 0; b < 8; ++b) atomicAdd(hp + b, acc[a][b] * wv);
        }
    }
}

__global__ void norm1_kernel(float* __restrict__ hacc, const float* __restrict__ s1) {
    int g = blockIdx.x * blockDim.x + threadIdx.x;
    if (g >= NN * DH) return;
    int n = g >> 9, o = g & 511;
    float v = hacc[g] / (s1[n * 8 + (o >> 6)] + 1e-16f);
    hacc[g] = v > 0.f ? v : 0.f;
}

// ---------------- qk2 = h @ alpha2  ([N,512] @ [512,32]) ----------------
__global__ void qk2_kernel(const float* __restrict__ h, const float* __restrict__ alpha2,
                           float* __restrict__ qk2) {
    __shared__ float Ht[TILE][129];
    int n0 = blockIdx.x * TILE;
    int tid = threadIdx.x;
    int to = tid >> 4, te = tid & 15;
    float acc[4][2] = {};
    for (int kc = 0; kc < 4; ++kc) {
        __syncthreads();
        for (int idx = tid; idx < TILE * 128; idx += 256) {
            int row = idx >> 7, i = idx & 127;
            int n = n0 + row;
            Ht[row][i] = (n < NN) ? h[(size_t)n * DH + kc * 128 + i] : 0.f;
        }
        __syncthreads();
        const float* Wp = alpha2 + (size_t)(kc * 128) * 32 + to * 2;
        for (int i = 0; i < 128; ++i) {
            float2 w = *(const float2*)(Wp + (size_t)i * 32);
            #pragma unroll
            for (int a = 0; a < 4; ++a) {
                float xv = Ht[te * 4 + a][i];
                acc[a][0] += xv * w.x; acc[a][1] += xv * w.y;
            }
        }
    }
    #pragma unroll
    for (int a = 0; a < 4; ++a) {
        int n = n0 + te * 4 + a;
        if (n < NN) {
            float2 o2; o2.x = acc[a][0]; o2.y = acc[a][1];
            *(float2*)(qk2 + (size_t)n * 32 + to * 2) = o2;
        }
    }
}

__global__ void elogit2_kernel(const int* __restrict__ ei, const int* __restrict__ et,
                               const float* __restrict__ qk2, float* __restrict__ e2,
                               float* __restrict__ s2) {
    int e = blockIdx.x * blockDim.x + threadIdx.x;
    if (e >= NE) return;
    int src = ei[e], dst = ei[NE + e], r = et[e];
    float l = qk2[(size_t)dst * 32 + r * 2] + qk2[(size_t)src * 32 + r * 2 + 1];
    l = l > 0.f ? l : 0.2f * l;
    float v = __expf(l);
    e2[e] = v;
    atomicAdd(&s2[dst], v);
}

// ---------------- layer2: relation-bucketed gather-GEMM + weighted atomic scatter ----------------
__global__ void l2_kernel(const float* __restrict__ h, const float* __restrict__ W2,
                          const int* __restrict__ ei, const int* __restrict__ border,
                          const int* __restrict__ tile_r, const int* __restrict__ tile_s,
                          const int* __restrict__ offs, const float* __restrict__ e2,
                          float* __restrict__ zacc) {
    int r = tile_r[blockIdx.x];
    if (r < 0) return;
    int start = tile_s[blockIdx.x];
    int cnt = offs[r + 1] - start; if (cnt > TILE) cnt = TILE;
    __shared__ float Ht[TILE][129];
    __shared__ float ev2[TILE];
    __shared__ int dstS[TILE], srcS[TILE];
    int tid = threadIdx.x;
    if (tid < TILE) {
        int sv = 0, dv = 0; float vv = 0.f;
        if (tid < cnt) { int e = border[start + tid]; sv = ei[e]; dv = ei[NE + e]; vv = e2[e]; }
        srcS[tid] = sv; dstS[tid] = dv; ev2[tid] = vv;
    }
    __syncthreads();
    int to = tid >> 4, te = tid & 15;
    float acc[4][8] = {};
    const float* Wbase = W2 + (size_t)r * DH * DOUT + to * 8;
    for (int kc = 0; kc < 4; ++kc) {
        if (kc) __syncthreads();
        for (int idx = tid; idx < TILE * 128; idx += 256) {
            int row = idx >> 7, i = idx & 127;
            Ht[row][i] = (row < cnt) ? h[(size_t)srcS[row] * DH + kc * 128 + i] : 0.f;
        }
        __syncthreads();
        const float* Wp = Wbase + (size_t)(kc * 128) * DOUT;
        for (int i = 0; i < 128; ++i) {
            const float* wr = Wp + (size_t)i * DOUT;
            float4 w0 = *(const float4*)(wr);
            float4 w1 = *(const float4*)(wr + 4);
            float w[8] = {w0.x, w0.y, w0.z, w0.w, w1.x, w1.y, w1.z, w1.w};
            #pragma unroll
            for (int a = 0; a < 4; ++a) {
                float xv = Ht[te * 4 + a][i];
                #pragma unroll
                for (int b = 0; b < 8; ++b) acc[a][b] += xv * w[b];
            }
        }
    }
    #pragma unroll
    for (int a = 0; a < 4; ++a) {
        int row = te * 4 + a;
        float wv = ev2[row];
        float* zp = zacc + (size_t)dstS[row] * DOUT + to * 8;
        #pragma unroll
        for (int b = 0; b < 8; ++b) atomicAdd(zp + b, acc[a][b] * wv);
    }
}

__global__ void norm2_kernel(float* __restrict__ zacc, const float* __restrict__ s2) {
    int g = blockIdx.x * blockDim.x + threadIdx.x;
    if (g >= NN * DOUT) return;
    int n = g >> 7;
    zacc[g] = zacc[g] / (s2[n] + 1e-16f);
}

// ---------------- link-prediction decoder ----------------
__global__ void decode_kernel(const float* __restrict__ z, const int* __restrict__ tgt,
                              const float* __restrict__ lw1, const float* __restrict__ lb1,
                              const float* __restrict__ lw2, const float* __restrict__ lb2,
                              float* __restrict__ out) {
    __shared__ float Zt[TILE][129];
    __shared__ float red[TILE][17];
    int t0 = blockIdx.x * TILE;
    int tid = threadIdx.x;
    int cnt = NT - t0; if (cnt > TILE) cnt = TILE;
    int to = tid >> 4, te = tid & 15;
    float acc[4][8] = {};
    for (int kc = 0; kc < 2; ++kc) {
        if (kc) __syncthreads();
        for (int idx = tid; idx < TILE * 128; idx += 256) {
            int row = idx >> 7, i = idx & 127;
            float v = 0.f;
            if (row < cnt) {
                int node = tgt[kc * NT + t0 + row];
                v = z[(size_t)node * DOUT + i];
            }
            Zt[row][i] = v;
        }
        __syncthreads();
        const float* Wp = lw1 + (size_t)(kc * 128) * DOUT + to * 8;
        for (int i = 0; i < 128; ++i) {
            const float* wr = Wp + (size_t)i * DOUT;
            float4 w0 = *(const float4*)(wr);
            float4 w1 = *(const float4*)(wr + 4);
            float w[8] = {w0.x, w0.y, w0.z, w0.w, w1.x, w1.y, w1.z, w1.w};
            #pragma unroll
            for (int a = 0; a < 4; ++a) {
                float xv = Zt[te * 4 + a][i];
                #pragma unroll
                for (int b = 0; b < 8; ++b) acc[a][b] += xv * w[b];
            }
        }
    }
    float lb[8], lw[8];
    #pragma unroll
    for (int b = 0; b < 8; ++b) { lb[b] = lb1[to * 8 + b]; lw[b] = lw2[to * 8 + b]; }
    __syncthreads();
    #pragma unroll
    for (int a = 0; a < 4; ++a) {
        float s = 0.f;
        #pragma unroll
        for (int b = 0; b < 8; ++b) {
            float hv = acc[a][b] + lb[b];
            hv = hv > 0.f ? hv : 0.f;
            s += hv * lw[b];
        }
        red[te * 4 + a][to] = s;
    }
    __syncthreads();
    if (tid < cnt) {
        float s = 0.f;
        #pragma unroll
        for (int g = 0; g < 16; ++g) s += red[tid][g];
        out[t0 + tid] = s + lb2[0];
    }
}

extern "C" void kernel_launch(void* const* d_in, const int* in_sizes, int n_in,
                              void* d_out, int out_size, void* d_ws, size_t ws_size,
                              hipStream_t stream) {
    const float* x   = (const float*)d_in[0];
    const int*   ei  = (const int*)d_in[1];
    const int*   et  = (const int*)d_in[2];
    const int*   tgt = (const int*)d_in[3];
    const float* W1  = (const float*)d_in[4];
    const float* aq1 = (const float*)d_in[5];
    const float* ak1 = (const float*)d_in[6];
    const float* W2  = (const float*)d_in[7];
    const float* aq2 = (const float*)d_in[8];
    const float* ak2 = (const float*)d_in[9];
    const float* lw1 = (const float*)d_in[10];
    const float* lb1 = (const float*)d_in[11];
    const float* lw2 = (const float*)d_in[12];
    const float* lb2 = (const float*)d_in[13];
    float* out = (float*)d_out;
    (void)in_sizes; (void)n_in; (void)out_size; (void)ws_size;

    char* ws = (char*)d_ws;
    size_t off = 0;
    auto alloc = [&](size_t bytes) -> void* {
        void* p = ws + off;
        off += (bytes + 255) & ~(size_t)255;
        return p;
    };
    // zero-init block (one memset covers these, including alignment padding)
    int*   cnt    = (int*)alloc(NR * sizeof(int));
    float* s1     = (float*)alloc((size_t)NN * 8 * 4);
    float* s2     = (float*)alloc((size_t)NN * 4);
    float* hacc   = (float*)alloc((size_t)NN * DH * 4);
    float* zacc   = (float*)alloc((size_t)NN * DOUT * 4);
    size_t zero_bytes = off;
    // no-init scratch
    float* alpha1 = (float*)alloc((size_t)128 * 256 * 4);
    float* alpha2 = (float*)alloc((size_t)512 * 32 * 4);
    float* qk1    = (float*)alloc((size_t)NN * 256 * 4);
    float* qk2v   = (float*)alloc((size_t)NN * 32 * 4);
    float* e1     = (float*)alloc((size_t)NE * 8 * 4);
    float* e2     = (float*)alloc((size_t)NE * 4);
    int*   offs   = (int*)alloc((NR + 1) * sizeof(int));
    int*   cursor = (int*)alloc(NR * sizeof(int));
    int*   border = (int*)alloc((size_t)NE * sizeof(int));
    int*   tile_r = (int*)alloc((size_t)NTILES * sizeof(int));
    int*   tile_s = (int*)alloc((size_t)NTILES * sizeof(int));

    hipMemsetAsync(ws, 0, zero_bytes, stream);
    alpha1_kernel<<<DIN, 256, 0, stream>>>(W1, aq1, ak1, alpha1);
    alpha2_kernel<<<(DH * 32 + 255) / 256, 256, 0, stream>>>(W2, aq2, ak2, alpha2);
    count_kernel<<<(NE + 255) / 256, 256, 0, stream>>>(et, cnt);
    scan_kernel<<<1, 64, 0, stream>>>(cnt, offs, cursor);
    tilemap_kernel<<<(NTILES + 255) / 256, 256, 0, stream>>>(offs, tile_r, tile_s);
    bucket_kernel<<<(NE + 255) / 256, 256, 0, stream>>>(et, cursor, border);
    qk1_kernel<<<(NN + TILE - 1) / TILE, 256, 0, stream>>>(x, alpha1, qk1);
    elogit1_kernel<<<(NE + 255) / 256, 256, 0, stream>>>(ei, et, qk1, e1, s1);
    l1_kernel<<<NTILES, 256, 0, stream>>>(x, W1, ei, border, tile_r, tile_s, offs, e1, hacc);
    norm1_kernel<<<(NN * DH + 255) / 256, 256, 0, stream>>>(hacc, s1);
    qk2_kernel<<<(NN + TILE - 1) / TILE, 256, 0, stream>>>(hacc, alpha2, qk2v);
    elogit2_kernel<<<(NE + 255) / 256, 256, 0, stream>>>(ei, et, qk2v, e2, s2);
    l2_kernel<<<NTILES, 256, 0, stream>>>(hacc, W2, ei, border, tile_r, tile_s, offs, e2, zacc);
    norm2_kernel<<<(NN * DOUT + 255) / 256, 256, 0, stream>>>(zacc, s2);
    decode_kernel<<<(NT + TILE - 1) / TILE, 256, 0, stream>>>(zacc, tgt, lw1, lb1, lw2, lb2, out);
}

// Round 2
// 2716.306 us; speedup vs baseline: 2.3976x; 2.3976x over previous
//
#include <hip/hip_runtime.h>
#include <cstdint>
#include <cstddef>

#define NN     20000
#define NE     320000
#define NR     16
#define DIN    128
#define DH     512
#define DOUT   128
#define NT     50000
#define TILE   64
#define CHUNKS 8
#define CHD    2500
#define NBUCKET (CHUNKS * NR)          // 128
#define MSGROWS 46080                  // max edges per chunk (40000 avg, +32 sigma safe)
#define MAXTPC  720                    // max GEMM tiles per chunk
#define NTILESMAX (NE / TILE + NBUCKET)

// ---------------- fold attention vectors into weights ----------------
__global__ void alpha1_kernel(const float* __restrict__ W1, const float* __restrict__ aq1,
                              const float* __restrict__ ak1, float* __restrict__ alpha1) {
    int i = blockIdx.x;            // 0..127
    int c = threadIdx.x;           // 0..255
    int r = c >> 4, s = (c >> 3) & 1, h = c & 7;
    const float* att = (s == 0 ? aq1 : ak1) + (r * 8 + h) * 64;
    const float* w = W1 + ((size_t)(r * DIN + i)) * DH + h * 64;
    float acc = 0.f;
    #pragma unroll 8
    for (int o = 0; o < 64; ++o) acc += w[o] * att[o];
    alpha1[i * 256 + c] = acc;
}

__global__ void alpha2_kernel(const float* __restrict__ W2, const float* __restrict__ aq2,
                              const float* __restrict__ ak2, float* __restrict__ alpha2) {
    int g = blockIdx.x * blockDim.x + threadIdx.x;
    if (g >= DH * 32) return;
    int i = g >> 5, c = g & 31;
    int r = c >> 1, s = c & 1;
    const float* att = (s == 0 ? aq2 : ak2) + r * DOUT;
    const float* w = W2 + ((size_t)(r * DH + i)) * DOUT;
    float acc = 0.f;
    #pragma unroll 8
    for (int o = 0; o < DOUT; ++o) acc += w[o] * att[o];
    alpha2[i * 32 + c] = acc;
}

// ---------------- sorts ----------------
// histogram over 128 (chunk,rel) buckets + 20000 dst bins
__global__ void hist_kernel(const int* __restrict__ ei, const int* __restrict__ et,
                            int* __restrict__ cnt128, int* __restrict__ cnt_d) {
    __shared__ int bins[NBUCKET];
    int t = threadIdx.x;
    if (t < NBUCKET) bins[t] = 0;
    __syncthreads();
    int e = blockIdx.x * 256 + t;
    if (e < NE) {
        int d = ei[NE + e];
        int key = (d / CHD) * NR + et[e];
        atomicAdd(&bins[key], 1);
        atomicAdd(&cnt_d[d], 1);
    }
    __syncthreads();
    if (t < NBUCKET && bins[t]) atomicAdd(&cnt128[t], bins[t]);
}

__global__ void scan128_kernel(const int* __restrict__ cnt128, int* __restrict__ boffs,
                               int* __restrict__ cursor128, int* __restrict__ cts) {
    if (threadIdx.x != 0) return;
    int acc = 0, tiles = 0;
    for (int b = 0; b < NBUCKET; ++b) {
        if ((b & (NR - 1)) == 0) cts[b >> 4] = tiles;
        boffs[b] = acc; cursor128[b] = acc;
        int cn = cnt128[b];
        tiles += (cn + TILE - 1) / TILE;
        acc += cn;
    }
    boffs[NBUCKET] = acc; cts[CHUNKS] = tiles;
}

__global__ void tilemap_kernel(const int* __restrict__ boffs, int* __restrict__ tile_b,
                               int* __restrict__ tile_s) {
    __shared__ int bo[NBUCKET + 1];
    int tid = threadIdx.x;
    if (tid <= NBUCKET) bo[tid] = boffs[tid];
    __syncthreads();
    int t = blockIdx.x * 256 + tid;
    if (t >= NTILESMAX) return;
    int acc = 0, bb = -1, ss = 0;
    for (int b = 0; b < NBUCKET; ++b) {
        int cn = bo[b + 1] - bo[b];
        int nt = (cn + TILE - 1) / TILE;
        if (t >= acc && t < acc + nt) { bb = b; ss = bo[b] + (t - acc) * TILE; }
        acc += nt;
    }
    tile_b[t] = bb; tile_s[t] = ss;
}

__global__ void bucket_place_kernel(const int* __restrict__ ei, const int* __restrict__ et,
                                    int* __restrict__ cursor128, int* __restrict__ border) {
    __shared__ int binc[NBUCKET], base_[NBUCKET], rank_[NBUCKET];
    int t = threadIdx.x;
    if (t < NBUCKET) { binc[t] = 0; rank_[t] = 0; }
    __syncthreads();
    int e = blockIdx.x * 256 + t;
    int key = -1;
    if (e < NE) { key = (ei[NE + e] / CHD) * NR + et[e]; atomicAdd(&binc[key], 1); }
    __syncthreads();
    if (t < NBUCKET && binc[t]) base_[t] = atomicAdd(&cursor128[t], binc[t]);
    __syncthreads();
    if (key >= 0) border[base_[key] + atomicAdd(&rank_[key], 1)] = e;
}

__global__ void scan_dst_kernel(const int* __restrict__ cnt_d, int* __restrict__ doffs,
                                int* __restrict__ cursor_d) {
    __shared__ int part[1024];
    int t = threadIdx.x;
    int base = t * 20;
    int s = 0;
    for (int i = 0; i < 20 && base + i < NN; ++i) s += cnt_d[base + i];
    part[t] = s;
    __syncthreads();
    for (int off = 1; off < 1024; off <<= 1) {
        int v = (t >= off) ? part[t - off] : 0;
        __syncthreads();
        part[t] += v;
        __syncthreads();
    }
    int run = part[t] - s;   // exclusive prefix
    for (int i = 0; i < 20 && base + i < NN; ++i) {
        doffs[base + i] = run; cursor_d[base + i] = run;
        run += cnt_d[base + i];
    }
    if (t == 1023) doffs[NN] = part[1023];
}

// dlist: border-positions grouped by dst; dedge: the edge ids (kills a dependent load)
__global__ void place_dst_kernel(const int* __restrict__ border, const int* __restrict__ ei,
                                 int* __restrict__ cursor_d, int* __restrict__ dlist,
                                 int* __restrict__ dedge) {
    int pos = blockIdx.x * 256 + threadIdx.x;
    if (pos >= NE) return;
    int e = border[pos];
    int d = ei[NE + e];
    int idx = atomicAdd(&cursor_d[d], 1);
    dlist[idx] = pos;
    dedge[idx] = e;
}

// ---------------- qk1 = x @ alpha1  ([N,128] @ [128,256]) ----------------
__global__ void qk1_kernel(const float* __restrict__ x, const float* __restrict__ alpha1,
                           float* __restrict__ qk1) {
    __shared__ float Xt[TILE][DIN + 1];
    int n0 = blockIdx.x * TILE;
    int tid = threadIdx.x;
    for (int idx = tid; idx < TILE * DIN; idx += 256) {
        int row = idx >> 7, i = idx & 127;
        int n = n0 + row;
        Xt[row][i] = (n < NN) ? x[(size_t)n * DIN + i] : 0.f;
    }
    __syncthreads();
    int to = tid >> 4, te = tid & 15;
    for (int c = 0; c < 2; ++c) {
        float acc[4][8] = {};
        const float* Wp = alpha1 + c * 128 + to * 8;
        for (int i = 0; i < DIN; ++i) {
            float4 w0 = *(const float4*)(Wp + (size_t)i * 256);
            float4 w1 = *(const float4*)(Wp + (size_t)i * 256 + 4);
            float w[8] = {w0.x, w0.y, w0.z, w0.w, w1.x, w1.y, w1.z, w1.w};
            #pragma unroll
            for (int a = 0; a < 4; ++a) {
                float xv = Xt[te * 4 + a][i];
                #pragma unroll
                for (int b = 0; b < 8; ++b) acc[a][b] += xv * w[b];
            }
        }
        #pragma unroll
        for (int a = 0; a < 4; ++a) {
            int n = n0 + te * 4 + a;
            if (n < NN) {
                float* op = qk1 + (size_t)n * 256 + c * 128 + to * 8;
                #pragma unroll
                for (int b = 0; b < 8; ++b) op[b] = acc[a][b];
            }
        }
    }
}

__global__ void elogit1_kernel(const int* __restrict__ ei, const int* __restrict__ et,
                               const float* __restrict__ qk1, float* __restrict__ e1) {
    int e = blockIdx.x * blockDim.x + threadIdx.x;
    if (e >= NE) return;
    int src = ei[e], dst = ei[NE + e], r = et[e];
    const float* qp = qk1 + (size_t)dst * 256 + r * 16;
    const float* kp = qk1 + (size_t)src * 256 + r * 16 + 8;
    float* ep = e1 + (size_t)e * 8;
    #pragma unroll
    for (int h = 0; h < 8; ++h) {
        float l = qp[h] + kp[h];
        l = l > 0.f ? l : 0.2f * l;
        ep[h] = __expf(l);
    }
}

// ---------------- layer1 GEMM per chunk: msg[row] = X[src] @ W1[r] ----------------
__global__ void l1_gemm_kernel(const float* __restrict__ x, const float* __restrict__ W1,
                               const int* __restrict__ ei, const int* __restrict__ border,
                               const int* __restrict__ tile_b, const int* __restrict__ tile_s,
                               const int* __restrict__ boffs, const int* __restrict__ cts,
                               int c, float* __restrict__ msg) {
    int t = cts[c] + blockIdx.x;
    if (t >= cts[c + 1]) return;
    int b = tile_b[t];
    int r = b & (NR - 1);
    int start = tile_s[t];
    int cstart = boffs[c * NR];
    int cnt = boffs[b + 1] - start; if (cnt > TILE) cnt = TILE;
    __shared__ float Xt[TILE][DIN + 1];
    __shared__ int srcS[TILE];
    int tid = threadIdx.x;
    if (tid < TILE) {
        int sv = 0;
        if (tid < cnt) { int e = border[start + tid]; sv = ei[e]; }
        srcS[tid] = sv;
    }
    __syncthreads();
    for (int idx = tid; idx < TILE * DIN; idx += 256) {
        int row = idx >> 7, i = idx & 127;
        Xt[row][i] = (row < cnt) ? x[(size_t)srcS[row] * DIN + i] : 0.f;
    }
    __syncthreads();
    int to = tid >> 4, te = tid & 15;
    const float* Wbase = W1 + (size_t)r * DIN * DH + to * 8;
    float* mbase = msg + (size_t)(start - cstart) * DH + to * 8;
    for (int cc = 0; cc < 4; ++cc) {
        float acc[4][8] = {};
        const float* Wp = Wbase + cc * 128;
        for (int i = 0; i < DIN; ++i) {
            const float* wr = Wp + (size_t)i * DH;
            float4 w0 = *(const float4*)(wr);
            float4 w1 = *(const float4*)(wr + 4);
            float w[8] = {w0.x, w0.y, w0.z, w0.w, w1.x, w1.y, w1.z, w1.w};
            #pragma unroll
            for (int a = 0; a < 4; ++a) {
                float xv = Xt[te * 4 + a][i];
                #pragma unroll
                for (int bb = 0; bb < 8; ++bb) acc[a][bb] += xv * w[bb];
            }
        }
        #pragma unroll
        for (int a = 0; a < 4; ++a) {
            int row = te * 4 + a;
            if (row < cnt) {
                float* mp = mbase + (size_t)row * DH + cc * 128;
                float4 o0; o0.x = acc[a][0]; o0.y = acc[a][1]; o0.z = acc[a][2]; o0.w = acc[a][3];
                float4 o1; o1.x = acc[a][4]; o1.y = acc[a][5]; o1.z = acc[a][6]; o1.w = acc[a][7];
                *(float4*)mp = o0;
                *(float4*)(mp + 4) = o1;
            }
        }
    }
}

// ---------------- layer1 aggregation: 4 waves per dst, 2 cols per lane ----------------
__global__ void l1_agg_kernel(const float* __restrict__ msg, const float* __restrict__ e1,
                              const int* __restrict__ dlist, const int* __restrict__ dedge,
                              const int* __restrict__ doffs, const int* __restrict__ boffs,
                              int c, float* __restrict__ hacc) {
    int tid = threadIdx.x;
    int wid = blockIdx.x * 4 + (tid >> 6);   // 0..9999
    int lane = tid & 63;
    int d = c * CHD + (wid >> 2);
    int q = wid & 3;
    int lo = doffs[d], hi = doffs[d + 1];
    int cstart = boffs[c * NR];
    int col = q * 128 + lane * 2;
    int h = col >> 6;
    float a0 = 0.f, a1 = 0.f, se = 0.f;
    for (int p = lo; p < hi; ++p) {
        int pos = dlist[p];
        int e = dedge[p];
        float w = e1[(size_t)e * 8 + h];
        se += w;
        const float* mp = msg + (size_t)(pos - cstart) * DH + col;
        float2 m = *(const float2*)mp;
        a0 += w * m.x; a1 += w * m.y;
    }
    float inv = 1.f / (se + 1e-16f);
    a0 *= inv; a1 *= inv;
    float2 o; o.x = a0 > 0.f ? a0 : 0.f; o.y = a1 > 0.f ? a1 : 0.f;
    *(float2*)(hacc + (size_t)d * DH + col) = o;
}

// ---------------- qk2 = h @ alpha2  ([N,512] @ [512,32]) ----------------
__global__ void qk2_kernel(const float* __restrict__ h, const float* __restrict__ alpha2,
                           float* __restrict__ qk2) {
    __shared__ float Ht[TILE][129];
    int n0 = blockIdx.x * TILE;
    int tid = threadIdx.x;
    int to = tid >> 4, te = tid & 15;
    float acc[4][2] = {};
    for (int kc = 0; kc < 4; ++kc) {
        __syncthreads();
        for (int idx = tid; idx < TILE * 128; idx += 256) {
            int row = idx >> 7, i = idx & 127;
            int n = n0 + row;
            Ht[row][i] = (n < NN) ? h[(size_t)n * DH + kc * 128 + i] : 0.f;
        }
        __syncthreads();
        const float* Wp = alpha2 + (size_t)(kc * 128) * 32 + to * 2;
        for (int i = 0; i < 128; ++i) {
            float2 w = *(const float2*)(Wp + (size_t)i * 32);
            #pragma unroll
            for (int a = 0; a < 4; ++a) {
                float xv = Ht[te * 4 + a][i];
                acc[a][0] += xv * w.x; acc[a][1] += xv * w.y;
            }
        }
    }
    #pragma unroll
    for (int a = 0; a < 4; ++a) {
        int n = n0 + te * 4 + a;
        if (n < NN) {
            float2 o2; o2.x = acc[a][0]; o2.y = acc[a][1];
            *(float2*)(qk2 + (size_t)n * 32 + to * 2) = o2;
        }
    }
}

__global__ void elogit2_kernel(const int* __restrict__ ei, const int* __restrict__ et,
                               const float* __restrict__ qk2, float* __restrict__ e2) {
    int e = blockIdx.x * blockDim.x + threadIdx.x;
    if (e >= NE) return;
    int src = ei[e], dst = ei[NE + e], r = et[e];
    float l = qk2[(size_t)dst * 32 + r * 2] + qk2[(size_t)src * 32 + r * 2 + 1];
    l = l > 0.f ? l : 0.2f * l;
    e2[e] = __expf(l);
}

// ---------------- layer2 GEMM per chunk: msg2[row] = H[src] @ W2[r] ----------------
__global__ void l2_gemm_kernel(const float* __restrict__ h, const float* __restrict__ W2,
                               const int* __restrict__ ei, const int* __restrict__ border,
                               const int* __restrict__ tile_b, const int* __restrict__ tile_s,
                               const int* __restrict__ boffs, const int* __restrict__ cts,
                               int c, float* __restrict__ msg2) {
    int t = cts[c] + blockIdx.x;
    if (t >= cts[c + 1]) return;
    int b = tile_b[t];
    int r = b & (NR - 1);
    int start = tile_s[t];
    int cstart = boffs[c * NR];
    int cnt = boffs[b + 1] - start; if (cnt > TILE) cnt = TILE;
    __shared__ float Ht[TILE][129];
    __shared__ int srcS[TILE];
    int tid = threadIdx.x;
    if (tid < TILE) {
        int sv = 0;
        if (tid < cnt) { int e = border[start + tid]; sv = ei[e]; }
        srcS[tid] = sv;
    }
    __syncthreads();
    int to = tid >> 4, te = tid & 15;
    float acc[4][8] = {};
    const float* Wbase = W2 + (size_t)r * DH * DOUT + to * 8;
    for (int kc = 0; kc < 4; ++kc) {
        if (kc) __syncthreads();
        for (int idx = tid; idx < TILE * 128; idx += 256) {
            int row = idx >> 7, i = idx & 127;
            Ht[row][i] = (row < cnt) ? h[(size_t)srcS[row] * DH + kc * 128 + i] : 0.f;
        }
        __syncthreads();
        const float* Wp = Wbase + (size_t)(kc * 128) * DOUT;
        for (int i = 0; i < 128; ++i) {
            const float* wr = Wp + (size_t)i * DOUT;
            float4 w0 = *(const float4*)(wr);
            float4 w1 = *(const float4*)(wr + 4);
            float w[8] = {w0.x, w0.y, w0.z, w0.w, w1.x, w1.y, w1.z, w1.w};
            #pragma unroll
            for (int a = 0; a < 4; ++a) {
                float xv = Ht[te * 4 + a][i];
                #pragma unroll
                for (int bb = 0; bb < 8; ++bb) acc[a][bb] += xv * w[bb];
            }
        }
    }
    #pragma unroll
    for (int a = 0; a < 4; ++a) {
        int row = te * 4 + a;
        if (row < cnt) {
            float* mp = msg2 + (size_t)(start - cstart + row) * DOUT + to * 8;
            float4 o0; o0.x = acc[a][0]; o0.y = acc[a][1]; o0.z = acc[a][2]; o0.w = acc[a][3];
            float4 o1; o1.x = acc[a][4]; o1.y = acc[a][5]; o1.z = acc[a][6]; o1.w = acc[a][7];
            *(float4*)mp = o0;
            *(float4*)(mp + 4) = o1;
        }
    }
}

// ---------------- layer2 aggregation: 2 waves per dst, 1 col per lane ----------------
__global__ void l2_agg_kernel(const float* __restrict__ msg2, const float* __restrict__ e2,
                              const int* __restrict__ dlist, const int* __restrict__ dedge,
                              const int* __restrict__ doffs, const int* __restrict__ boffs,
                              int c, float* __restrict__ zacc) {
    int tid = threadIdx.x;
    int wid = blockIdx.x * 4 + (tid >> 6);   // 0..4999
    int lane = tid & 63;
    int d = c * CHD + (wid >> 1);
    int q = wid & 1;
    int lo = doffs[d], hi = doffs[d + 1];
    int cstart = boffs[c * NR];
    int col = q * 64 + lane;
    float a0 = 0.f, se = 0.f;
    for (int p = lo; p < hi; ++p) {
        int pos = dlist[p];
        float w = e2[dedge[p]];
        se += w;
        a0 += w * msg2[(size_t)(pos - cstart) * DOUT + col];
    }
    zacc[(size_t)d * DOUT + col] = a0 / (se + 1e-16f);
}

// ---------------- link-prediction decoder ----------------
__global__ void decode_kernel(const float* __restrict__ z, const int* __restrict__ tgt,
                              const float* __restrict__ lw1, const float* __restrict__ lb1,
                              const float* __restrict__ lw2, const float* __restrict__ lb2,
                              float* __restrict__ out) {
    __shared__ float Zt[TILE][129];
    __shared__ float red[TILE][17];
    int t0 = blockIdx.x * TILE;
    int tid = threadIdx.x;
    int cnt = NT - t0; if (cnt > TILE) cnt = TILE;
    int to = tid >> 4, te = tid & 15;
    float acc[4][8] = {};
    for (int kc = 0; kc < 2; ++kc) {
        if (kc) __syncthreads();
        for (int idx = tid; idx < TILE * 128; idx += 256) {
            int row = idx >> 7, i = idx & 127;
            float v = 0.f;
            if (row < cnt) {
                int node = tgt[kc * NT + t0 + row];
                v = z[(size_t)node * DOUT + i];
            }
            Zt[row][i] = v;
        }
        __syncthreads();
        const float* Wp = lw1 + (size_t)(kc * 128) * DOUT + to * 8;
        for (int i = 0; i < 128; ++i) {
            const float* wr = Wp + (size_t)i * DOUT;
            float4 w0 = *(const float4*)(wr);
            float4 w1 = *(const float4*)(wr + 4);
            float w[8] = {w0.x, w0.y, w0.z, w0.w, w1.x, w1.y, w1.z, w1.w};
            #pragma unroll
            for (int a = 0; a < 4; ++a) {
                float xv = Zt[te * 4 + a][i];
                #pragma unroll
                for (int b = 0; b < 8; ++b) acc[a][b] += xv * w[b];
            }
        }
    }
    float lb[8], lw[8];
    #pragma unroll
    for (int b = 0; b < 8; ++b) { lb[b] = lb1[to * 8 + b]; lw[b] = lw2[to * 8 + b]; }
    __syncthreads();
    #pragma unroll
    for (int a = 0; a < 4; ++a) {
        float s = 0.f;
        #pragma unroll
        for (int b = 0; b < 8; ++b) {
            float hv = acc[a][b] + lb[b];
            hv = hv > 0.f ? hv : 0.f;
            s += hv * lw[b];
        }
        red[te * 4 + a][to] = s;
    }
    __syncthreads();
    if (tid < cnt) {
        float s = 0.f;
        #pragma unroll
        for (int g = 0; g < 16; ++g) s += red[tid][g];
        out[t0 + tid] = s + lb2[0];
    }
}

extern "C" void kernel_launch(void* const* d_in, const int* in_sizes, int n_in,
                              void* d_out, int out_size, void* d_ws, size_t ws_size,
                              hipStream_t stream) {
    const float* x   = (const float*)d_in[0];
    const int*   ei  = (const int*)d_in[1];
    const int*   et  = (const int*)d_in[2];
    const int*   tgt = (const int*)d_in[3];
    const float* W1  = (const float*)d_in[4];
    const float* aq1 = (const float*)d_in[5];
    const float* ak1 = (const float*)d_in[6];
    const float* W2  = (const float*)d_in[7];
    const float* aq2 = (const float*)d_in[8];
    const float* ak2 = (const float*)d_in[9];
    const float* lw1 = (const float*)d_in[10];
    const float* lb1 = (const float*)d_in[11];
    const float* lw2 = (const float*)d_in[12];
    const float* lb2 = (const float*)d_in[13];
    float* out = (float*)d_out;
    (void)in_sizes; (void)n_in; (void)out_size; (void)ws_size;

    char* ws = (char*)d_ws;
    size_t off = 0;
    auto alloc = [&](size_t bytes) -> void* {
        void* p = ws + off;
        off += (bytes + 255) & ~(size_t)255;
        return p;
    };
    // zero-init block: histograms only
    int*   cnt128 = (int*)alloc(NBUCKET * sizeof(int));
    int*   cnt_d  = (int*)alloc((size_t)NN * sizeof(int));
    size_t zero_bytes = off;
    // no-init scratch
    int*   boffs    = (int*)alloc((NBUCKET + 1) * sizeof(int));
    int*   cursor128= (int*)alloc(NBUCKET * sizeof(int));
    int*   cts      = (int*)alloc((CHUNKS + 1) * sizeof(int));
    int*   doffs    = (int*)alloc((size_t)(NN + 1) * sizeof(int));
    int*   cursor_d = (int*)alloc((size_t)NN * sizeof(int));
    int*   border   = (int*)alloc((size_t)NE * sizeof(int));
    int*   dlist    = (int*)alloc((size_t)NE * sizeof(int));
    int*   dedge    = (int*)alloc((size_t)NE * sizeof(int));
    int*   tile_b   = (int*)alloc((size_t)NTILESMAX * sizeof(int));
    int*   tile_s   = (int*)alloc((size_t)NTILESMAX * sizeof(int));
    float* alpha1   = (float*)alloc((size_t)128 * 256 * 4);
    float* alpha2   = (float*)alloc((size_t)512 * 32 * 4);
    float* qk1      = (float*)alloc((size_t)NN * 256 * 4);
    float* qk2v     = (float*)alloc((size_t)NN * 32 * 4);
    float* e1       = (float*)alloc((size_t)NE * 8 * 4);
    float* e2       = (float*)alloc((size_t)NE * 4);
    float* hacc     = (float*)alloc((size_t)NN * DH * 4);
    float* zacc     = (float*)alloc((size_t)NN * DOUT * 4);
    float* msg      = (float*)alloc((size_t)MSGROWS * DH * 4);   // reused as msg2
    float* msg2     = msg;

    hipMemsetAsync(ws, 0, zero_bytes, stream);
    alpha1_kernel<<<DIN, 256, 0, stream>>>(W1, aq1, ak1, alpha1);
    alpha2_kernel<<<(DH * 32 + 255) / 256, 256, 0, stream>>>(W2, aq2, ak2, alpha2);
    hist_kernel<<<(NE + 255) / 256, 256, 0, stream>>>(ei, et, cnt128, cnt_d);
    scan128_kernel<<<1, 64, 0, stream>>>(cnt128, boffs, cursor128, cts);
    tilemap_kernel<<<(NTILESMAX + 255) / 256, 256, 0, stream>>>(boffs, tile_b, tile_s);
    bucket_place_kernel<<<(NE + 255) / 256, 256, 0, stream>>>(ei, et, cursor128, border);
    scan_dst_kernel<<<1, 1024, 0, stream>>>(cnt_d, doffs, cursor_d);
    place_dst_kernel<<<(NE + 255) / 256, 256, 0, stream>>>(border, ei, cursor_d, dlist, dedge);
    qk1_kernel<<<(NN + TILE - 1) / TILE, 256, 0, stream>>>(x, alpha1, qk1);
    elogit1_kernel<<<(NE + 255) / 256, 256, 0, stream>>>(ei, et, qk1, e1);
    for (int c = 0; c < CHUNKS; ++c) {
        l1_gemm_kernel<<<MAXTPC, 256, 0, stream>>>(x, W1, ei, border, tile_b, tile_s, boffs, cts, c, msg);
        l1_agg_kernel<<<CHD, 256, 0, stream>>>(msg, e1, dlist, dedge, doffs, boffs, c, hacc);
    }
    qk2_kernel<<<(NN + TILE - 1) / TILE, 256, 0, stream>>>(hacc, alpha2, qk2v);
    elogit2_kernel<<<(NE + 255) / 256, 256, 0, stream>>>(ei, et, qk2v, e2);
    for (int c = 0; c < CHUNKS; ++c) {
        l2_gemm_kernel<<<MAXTPC, 256, 0, stream>>>(hacc, W2, ei, border, tile_b, tile_s, boffs, cts, c, msg2);
        l2_agg_kernel<<<(CHD + 1) / 2, 256, 0, stream>>>(msg2, e2, dlist, dedge, doffs, boffs, c, zacc);
    }
    decode_kernel<<<(NT + TILE - 1) / TILE, 256, 0, stream>>>(zacc, tgt, lw1, lb1, lw2, lb2, out);
}

// Round 3
// 2467.696 us; speedup vs baseline: 2.6391x; 1.1007x over previous
//
#include <hip/hip_runtime.h>
#include <cstdint>
#include <cstddef>

#define NN     20000
#define NE     320000
#define NR     16
#define DIN    128
#define DH     512
#define DOUT   128
#define NT     50000
#define TILE   64
#define CHUNKS 12
#define CHD    1667
#define NBUCKET (CHUNKS * NR)          // 192
#define MSGROWS 28672                  // max edges per chunk (~26.7k avg, +12 sigma)
#define MAXTPC  512                    // max GEMM tiles per chunk
#define NTILESMAX (NE / TILE + NBUCKET)

typedef __attribute__((ext_vector_type(8))) short bf16x8;
typedef __attribute__((ext_vector_type(4))) float f32x4;

__device__ __forceinline__ unsigned short f2bf(float x) {
    unsigned int b = __float_as_uint(x);
    b = b + 0x7fffu + ((b >> 16) & 1u);
    return (unsigned short)(b >> 16);
}
__device__ __forceinline__ float bf2f(unsigned short u) {
    return __uint_as_float(((unsigned int)u) << 16);
}

// ---------------- fold attention vectors into weights ----------------
__global__ void alpha1_kernel(const float* __restrict__ W1, const float* __restrict__ aq1,
                              const float* __restrict__ ak1, float* __restrict__ alpha1) {
    int i = blockIdx.x;            // 0..127
    int c = threadIdx.x;           // 0..255
    int r = c >> 4, s = (c >> 3) & 1, h = c & 7;
    const float* att = (s == 0 ? aq1 : ak1) + (r * 8 + h) * 64;
    const float* w = W1 + ((size_t)(r * DIN + i)) * DH + h * 64;
    float acc = 0.f;
    #pragma unroll 8
    for (int o = 0; o < 64; ++o) acc += w[o] * att[o];
    alpha1[i * 256 + c] = acc;
}

__global__ void alpha2_kernel(const float* __restrict__ W2, const float* __restrict__ aq2,
                              const float* __restrict__ ak2, float* __restrict__ alpha2) {
    int g = blockIdx.x * blockDim.x + threadIdx.x;
    if (g >= DH * 32) return;
    int i = g >> 5, c = g & 31;
    int r = c >> 1, s = c & 1;
    const float* att = (s == 0 ? aq2 : ak2) + r * DOUT;
    const float* w = W2 + ((size_t)(r * DH + i)) * DOUT;
    float acc = 0.f;
    #pragma unroll 8
    for (int o = 0; o < DOUT; ++o) acc += w[o] * att[o];
    alpha2[i * 32 + c] = acc;
}

// ---------------- bf16 hi/lo precompute ----------------
__global__ void split_x_kernel(const float* __restrict__ x, unsigned short* __restrict__ xhi,
                               unsigned short* __restrict__ xlo) {
    int g = blockIdx.x * 256 + threadIdx.x;
    if (g >= NN * DIN / 4) return;
    float4 v = ((const float4*)x)[g];
    ushort4 h, l;
    h.x = f2bf(v.x); l.x = f2bf(v.x - bf2f(h.x));
    h.y = f2bf(v.y); l.y = f2bf(v.y - bf2f(h.y));
    h.z = f2bf(v.z); l.z = f2bf(v.z - bf2f(h.z));
    h.w = f2bf(v.w); l.w = f2bf(v.w - bf2f(h.w));
    ((ushort4*)xhi)[g] = h;
    ((ushort4*)xlo)[g] = l;
}

// W1 [16][128][512] -> W1T hi/lo [16][512][128]
__global__ void splitW1T_kernel(const float* __restrict__ W1, unsigned short* __restrict__ Whi,
                                unsigned short* __restrict__ Wlo) {
    __shared__ float T[128 * 65];
    int r = blockIdx.x >> 3;
    int ob = blockIdx.x & 7;
    int tid = threadIdx.x;
    for (int idx = tid; idx < 128 * 64; idx += 256) {
        int i = idx >> 6, o = idx & 63;
        T[i * 65 + o] = W1[((size_t)(r * DIN + i)) * DH + ob * 64 + o];
    }
    __syncthreads();
    for (int idx = tid; idx < 64 * 128; idx += 256) {
        int o = idx >> 7, i = idx & 127;
        float v = T[i * 65 + o];
        unsigned short h = f2bf(v);
        size_t off = ((size_t)r * DH + ob * 64 + o) * DIN + i;
        Whi[off] = h;
        Wlo[off] = f2bf(v - bf2f(h));
    }
}

// W2 [16][512][128] -> W2T hi/lo [16][128][512]
__global__ void splitW2T_kernel(const float* __restrict__ W2, unsigned short* __restrict__ Whi,
                                unsigned short* __restrict__ Wlo) {
    __shared__ float T[128 * 65];
    int r = blockIdx.x >> 1;
    int ob = blockIdx.x & 1;
    int tid = threadIdx.x;
    for (int kc = 0; kc < 4; ++kc) {
        if (kc) __syncthreads();
        for (int idx = tid; idx < 128 * 64; idx += 256) {
            int k = idx >> 6, o = idx & 63;
            T[k * 65 + o] = W2[((size_t)(r * DH + kc * 128 + k)) * DOUT + ob * 64 + o];
        }
        __syncthreads();
        for (int idx = tid; idx < 64 * 128; idx += 256) {
            int o = idx >> 7, k = idx & 127;
            float v = T[k * 65 + o];
            unsigned short h = f2bf(v);
            size_t off = ((size_t)r * DOUT + ob * 64 + o) * DH + kc * 128 + k;
            Whi[off] = h;
            Wlo[off] = f2bf(v - bf2f(h));
        }
    }
}

// ---------------- sorts ----------------
__global__ void hist_kernel(const int* __restrict__ ei, const int* __restrict__ et,
                            int* __restrict__ cnt, int* __restrict__ cnt_d) {
    __shared__ int bins[NBUCKET];
    int t = threadIdx.x;
    if (t < NBUCKET) bins[t] = 0;
    __syncthreads();
    int e = blockIdx.x * 256 + t;
    if (e < NE) {
        int d = ei[NE + e];
        int key = (d / CHD) * NR + et[e];
        atomicAdd(&bins[key], 1);
        atomicAdd(&cnt_d[d], 1);
    }
    __syncthreads();
    if (t < NBUCKET && bins[t]) atomicAdd(&cnt[t], bins[t]);
}

__global__ void scan_bkt_kernel(const int* __restrict__ cnt, int* __restrict__ boffs,
                                int* __restrict__ cursor, int* __restrict__ cts) {
    if (threadIdx.x != 0) return;
    int acc = 0, tiles = 0;
    for (int b = 0; b < NBUCKET; ++b) {
        if ((b & (NR - 1)) == 0) cts[b >> 4] = tiles;
        boffs[b] = acc; cursor[b] = acc;
        int cn = cnt[b];
        tiles += (cn + TILE - 1) / TILE;
        acc += cn;
    }
    boffs[NBUCKET] = acc; cts[CHUNKS] = tiles;
}

__global__ void tilemap_kernel(const int* __restrict__ boffs, int* __restrict__ tile_b,
                               int* __restrict__ tile_s) {
    __shared__ int bo[NBUCKET + 1];
    int tid = threadIdx.x;
    if (tid <= NBUCKET) bo[tid] = boffs[tid];
    __syncthreads();
    int t = blockIdx.x * 256 + tid;
    if (t >= NTILESMAX) return;
    int acc = 0, bb = -1, ss = 0;
    for (int b = 0; b < NBUCKET; ++b) {
        int cn = bo[b + 1] - bo[b];
        int nt = (cn + TILE - 1) / TILE;
        if (t >= acc && t < acc + nt) { bb = b; ss = bo[b] + (t - acc) * TILE; }
        acc += nt;
    }
    tile_b[t] = bb; tile_s[t] = ss;
}

__global__ void bucket_place_kernel(const int* __restrict__ ei, const int* __restrict__ et,
                                    int* __restrict__ cursor, int* __restrict__ border) {
    __shared__ int binc[NBUCKET], base_[NBUCKET], rank_[NBUCKET];
    int t = threadIdx.x;
    if (t < NBUCKET) { binc[t] = 0; rank_[t] = 0; }
    __syncthreads();
    int e = blockIdx.x * 256 + t;
    int key = -1;
    if (e < NE) { key = (ei[NE + e] / CHD) * NR + et[e]; atomicAdd(&binc[key], 1); }
    __syncthreads();
    if (t < NBUCKET && binc[t]) base_[t] = atomicAdd(&cursor[t], binc[t]);
    __syncthreads();
    if (key >= 0) border[base_[key] + atomicAdd(&rank_[key], 1)] = e;
}

__global__ void scan_dst_kernel(const int* __restrict__ cnt_d, int* __restrict__ doffs,
                                int* __restrict__ cursor_d) {
    __shared__ int part[1024];
    int t = threadIdx.x;
    int base = t * 20;
    int s = 0;
    for (int i = 0; i < 20 && base + i < NN; ++i) s += cnt_d[base + i];
    part[t] = s;
    __syncthreads();
    for (int off = 1; off < 1024; off <<= 1) {
        int v = (t >= off) ? part[t - off] : 0;
        __syncthreads();
        part[t] += v;
        __syncthreads();
    }
    int run = part[t] - s;
    for (int i = 0; i < 20 && base + i < NN; ++i) {
        doffs[base + i] = run; cursor_d[base + i] = run;
        run += cnt_d[base + i];
    }
    if (t == 1023) doffs[NN] = part[1023];
}

__global__ void place_dst_kernel(const int* __restrict__ border, const int* __restrict__ ei,
                                 int* __restrict__ cursor_d, int* __restrict__ dlist,
                                 int* __restrict__ dedge) {
    int pos = blockIdx.x * 256 + threadIdx.x;
    if (pos >= NE) return;
    int e = border[pos];
    int d = ei[NE + e];
    int idx = atomicAdd(&cursor_d[d], 1);
    dlist[idx] = pos;
    dedge[idx] = e;
}

// ---------------- qk1 = x @ alpha1  ([N,128] @ [128,256]) ----------------
__global__ void qk1_kernel(const float* __restrict__ x, const float* __restrict__ alpha1,
                           float* __restrict__ qk1) {
    __shared__ float Xt[TILE][DIN + 1];
    int n0 = blockIdx.x * TILE;
    int tid = threadIdx.x;
    for (int idx = tid; idx < TILE * DIN; idx += 256) {
        int row = idx >> 7, i = idx & 127;
        int n = n0 + row;
        Xt[row][i] = (n < NN) ? x[(size_t)n * DIN + i] : 0.f;
    }
    __syncthreads();
    int to = tid >> 4, te = tid & 15;
    for (int c = 0; c < 2; ++c) {
        float acc[4][8] = {};
        const float* Wp = alpha1 + c * 128 + to * 8;
        for (int i = 0; i < DIN; ++i) {
            float4 w0 = *(const float4*)(Wp + (size_t)i * 256);
            float4 w1 = *(const float4*)(Wp + (size_t)i * 256 + 4);
            float w[8] = {w0.x, w0.y, w0.z, w0.w, w1.x, w1.y, w1.z, w1.w};
            #pragma unroll
            for (int a = 0; a < 4; ++a) {
                float xv = Xt[te * 4 + a][i];
                #pragma unroll
                for (int b = 0; b < 8; ++b) acc[a][b] += xv * w[b];
            }
        }
        #pragma unroll
        for (int a = 0; a < 4; ++a) {
            int n = n0 + te * 4 + a;
            if (n < NN) {
                float* op = qk1 + (size_t)n * 256 + c * 128 + to * 8;
                #pragma unroll
                for (int b = 0; b < 8; ++b) op[b] = acc[a][b];
            }
        }
    }
}

__global__ void elogit1_kernel(const int* __restrict__ ei, const int* __restrict__ et,
                               const float* __restrict__ qk1, float* __restrict__ e1) {
    int e = blockIdx.x * blockDim.x + threadIdx.x;
    if (e >= NE) return;
    int src = ei[e], dst = ei[NE + e], r = et[e];
    const float* qp = qk1 + (size_t)dst * 256 + r * 16;
    const float* kp = qk1 + (size_t)src * 256 + r * 16 + 8;
    float* ep = e1 + (size_t)e * 8;
    #pragma unroll
    for (int h = 0; h < 8; ++h) {
        float l = qp[h] + kp[h];
        l = l > 0.f ? l : 0.2f * l;
        ep[h] = __expf(l);
    }
}

// ---------------- layer1 GEMM (MFMA, split bf16): msg[row][512] = X[src] @ W1[r] ----------------
__global__ void l1_gemm_kernel(const unsigned short* __restrict__ xhi, const unsigned short* __restrict__ xlo,
                               const unsigned short* __restrict__ W1Thi, const unsigned short* __restrict__ W1Tlo,
                               const int* __restrict__ ei, const int* __restrict__ border,
                               const int* __restrict__ tile_b, const int* __restrict__ tile_s,
                               const int* __restrict__ boffs, const int* __restrict__ cts,
                               int c, float* __restrict__ msg) {
    int t = cts[c] + blockIdx.x;
    if (t >= cts[c + 1]) return;
    int b = tile_b[t];
    int r = b & (NR - 1);
    int start = tile_s[t];
    int cstart = boffs[c * NR];
    int cnt = boffs[b + 1] - start; if (cnt > TILE) cnt = TILE;
    __shared__ __align__(16) unsigned short Ah[64 * 128];
    __shared__ __align__(16) unsigned short Al[64 * 128];
    __shared__ int srcS[TILE];
    int tid = threadIdx.x;
    if (tid < TILE) {
        int sv = 0;
        if (tid < cnt) { int e = border[start + tid]; sv = ei[e]; }
        srcS[tid] = sv;
    }
    __syncthreads();
    {
        int row = tid >> 2, seg = tid & 3;
        const uint4* ph = (const uint4*)(xhi + (size_t)srcS[row] * DIN + seg * 32);
        const uint4* pl = (const uint4*)(xlo + (size_t)srcS[row] * DIN + seg * 32);
        unsigned rb = row * 256, sw = (row & 7) << 4;
        #pragma unroll
        for (int i = 0; i < 4; ++i) {
            unsigned off = (rb + seg * 64 + i * 16) ^ sw;
            *(uint4*)((char*)Ah + off) = ph[i];
            *(uint4*)((char*)Al + off) = pl[i];
        }
    }
    __syncthreads();
    int w = tid >> 6, lane = tid & 63;
    int l15 = lane & 15, l4 = lane >> 4;
    const unsigned short* Bh = W1Thi + ((size_t)r * DH + w * 128 + l15) * DIN + l4 * 8;
    const unsigned short* Bl = W1Tlo + ((size_t)r * DH + w * 128 + l15) * DIN + l4 * 8;
    f32x4 acc[4][8];
    #pragma unroll
    for (int m = 0; m < 4; ++m)
        #pragma unroll
        for (int n = 0; n < 8; ++n) acc[m][n] = (f32x4){0.f, 0.f, 0.f, 0.f};
    #pragma unroll
    for (int mg = 0; mg < 2; ++mg) {
        bf16x8 ah[2][4], al[2][4];
        #pragma unroll
        for (int mm = 0; mm < 2; ++mm) {
            int row = (mg * 2 + mm) * 16 + l15;
            unsigned rb = row * 256, sw = (row & 7) << 4;
            #pragma unroll
            for (int k = 0; k < 4; ++k) {
                unsigned off = (rb + k * 64 + l4 * 16) ^ sw;
                ah[mm][k] = *(const bf16x8*)((const char*)Ah + off);
                al[mm][k] = *(const bf16x8*)((const char*)Al + off);
            }
        }
        #pragma unroll
        for (int n = 0; n < 8; ++n) {
            #pragma unroll
            for (int k = 0; k < 4; ++k) {
                bf16x8 bh = *(const bf16x8*)(Bh + (size_t)n * 16 * DIN + k * 32);
                bf16x8 bl = *(const bf16x8*)(Bl + (size_t)n * 16 * DIN + k * 32);
                #pragma unroll
                for (int mm = 0; mm < 2; ++mm) {
                    int m = mg * 2 + mm;
                    acc[m][n] = __builtin_amdgcn_mfma_f32_16x16x32_bf16(ah[mm][k], bh, acc[m][n], 0, 0, 0);
                    acc[m][n] = __builtin_amdgcn_mfma_f32_16x16x32_bf16(ah[mm][k], bl, acc[m][n], 0, 0, 0);
                    acc[m][n] = __builtin_amdgcn_mfma_f32_16x16x32_bf16(al[mm][k], bh, acc[m][n], 0, 0, 0);
                }
            }
        }
    }
    float* mb = msg + (size_t)(start - cstart) * DH + w * 128;
    #pragma unroll
    for (int m = 0; m < 4; ++m) {
        int row0 = m * 16 + l4 * 4;
        #pragma unroll
        for (int rg = 0; rg < 4; ++rg) {
            int row = row0 + rg;
            if (row < cnt) {
                float* mp = mb + (size_t)row * DH;
                #pragma unroll
                for (int n = 0; n < 8; ++n) mp[n * 16 + l15] = acc[m][n][rg];
            }
        }
    }
}

// ---------------- layer1 agg: 4 waves per dst; write h as bf16 hi/lo ----------------
__global__ void l1_agg_kernel(const float* __restrict__ msg, const float* __restrict__ e1,
                              const int* __restrict__ dlist, const int* __restrict__ dedge,
                              const int* __restrict__ doffs, const int* __restrict__ boffs,
                              int c, unsigned short* __restrict__ hhi, unsigned short* __restrict__ hlo) {
    int tid = threadIdx.x;
    int d = c * CHD + blockIdx.x;
    if (d >= NN) return;
    int q = tid >> 6, lane = tid & 63;
    int lo_ = doffs[d], hi_ = doffs[d + 1];
    int cstart = boffs[c * NR];
    int col = q * 128 + lane * 2;
    int head = col >> 6;
    float a0 = 0.f, a1 = 0.f, se = 0.f;
    for (int p = lo_; p < hi_; ++p) {
        int pos = dlist[p];
        float wgt = e1[(size_t)dedge[p] * 8 + head];
        se += wgt;
        float2 m = *(const float2*)(msg + (size_t)(pos - cstart) * DH + col);
        a0 += wgt * m.x; a1 += wgt * m.y;
    }
    float inv = 1.f / (se + 1e-16f);
    a0 *= inv; a1 *= inv;
    a0 = a0 > 0.f ? a0 : 0.f;
    a1 = a1 > 0.f ? a1 : 0.f;
    ushort2 h2, l2v;
    h2.x = f2bf(a0); l2v.x = f2bf(a0 - bf2f(h2.x));
    h2.y = f2bf(a1); l2v.y = f2bf(a1 - bf2f(h2.y));
    *(ushort2*)(hhi + (size_t)d * DH + col) = h2;
    *(ushort2*)(hlo + (size_t)d * DH + col) = l2v;
}

// ---------------- qk2 = h @ alpha2  ([N,512] @ [512,32]) ----------------
__global__ void qk2_kernel(const unsigned short* __restrict__ hhi, const unsigned short* __restrict__ hlo,
                           const float* __restrict__ alpha2, float* __restrict__ qk2) {
    __shared__ float Ht[TILE][129];
    int n0 = blockIdx.x * TILE;
    int tid = threadIdx.x;
    int to = tid >> 4, te = tid & 15;
    float acc[4][2] = {};
    for (int kc = 0; kc < 4; ++kc) {
        __syncthreads();
        for (int idx = tid; idx < TILE * 32; idx += 256) {
            int row = idx >> 5, i4 = (idx & 31) * 4;
            int n = n0 + row;
            float v0 = 0.f, v1 = 0.f, v2 = 0.f, v3 = 0.f;
            if (n < NN) {
                ushort4 hv = *(const ushort4*)(hhi + (size_t)n * DH + kc * 128 + i4);
                ushort4 lv = *(const ushort4*)(hlo + (size_t)n * DH + kc * 128 + i4);
                v0 = bf2f(hv.x) + bf2f(lv.x);
                v1 = bf2f(hv.y) + bf2f(lv.y);
                v2 = bf2f(hv.z) + bf2f(lv.z);
                v3 = bf2f(hv.w) + bf2f(lv.w);
            }
            Ht[row][i4] = v0; Ht[row][i4 + 1] = v1; Ht[row][i4 + 2] = v2; Ht[row][i4 + 3] = v3;
        }
        __syncthreads();
        const float* Wp = alpha2 + (size_t)(kc * 128) * 32 + to * 2;
        for (int i = 0; i < 128; ++i) {
            float2 w = *(const float2*)(Wp + (size_t)i * 32);
            #pragma unroll
            for (int a = 0; a < 4; ++a) {
                float xv = Ht[te * 4 + a][i];
                acc[a][0] += xv * w.x; acc[a][1] += xv * w.y;
            }
        }
    }
    #pragma unroll
    for (int a = 0; a < 4; ++a) {
        int n = n0 + te * 4 + a;
        if (n < NN) {
            float2 o2; o2.x = acc[a][0]; o2.y = acc[a][1];
            *(float2*)(qk2 + (size_t)n * 32 + to * 2) = o2;
        }
    }
}

__global__ void elogit2_kernel(const int* __restrict__ ei, const int* __restrict__ et,
                               const float* __restrict__ qk2, float* __restrict__ e2) {
    int e = blockIdx.x * blockDim.x + threadIdx.x;
    if (e >= NE) return;
    int src = ei[e], dst = ei[NE + e], r = et[e];
    float l = qk2[(size_t)dst * 32 + r * 2] + qk2[(size_t)src * 32 + r * 2 + 1];
    l = l > 0.f ? l : 0.2f * l;
    e2[e] = __expf(l);
}

// ---------------- layer2 GEMM (MFMA, split bf16): msg2[row][128] = H[src] @ W2[r] ----------------
__global__ void l2_gemm_kernel(const unsigned short* __restrict__ hhi, const unsigned short* __restrict__ hlo,
                               const unsigned short* __restrict__ W2Thi, const unsigned short* __restrict__ W2Tlo,
                               const int* __restrict__ ei, const int* __restrict__ border,
                               const int* __restrict__ tile_b, const int* __restrict__ tile_s,
                               const int* __restrict__ boffs, const int* __restrict__ cts,
                               int c, float* __restrict__ msg2) {
    int t = cts[c] + blockIdx.x;
    if (t >= cts[c + 1]) return;
    int b = tile_b[t];
    int r = b & (NR - 1);
    int start = tile_s[t];
    int cstart = boffs[c * NR];
    int cnt = boffs[b + 1] - start; if (cnt > TILE) cnt = TILE;
    __shared__ __align__(16) unsigned short Ah[64 * 128];
    __shared__ __align__(16) unsigned short Al[64 * 128];
    __shared__ int srcS[TILE];
    int tid = threadIdx.x;
    if (tid < TILE) {
        int sv = 0;
        if (tid < cnt) { int e = border[start + tid]; sv = ei[e]; }
        srcS[tid] = sv;
    }
    __syncthreads();
    int w = tid >> 6, lane = tid & 63;
    int l15 = lane & 15, l4 = lane >> 4;
    const unsigned short* Bh = W2Thi + ((size_t)r * DOUT + w * 32 + l15) * DH + l4 * 8;
    const unsigned short* Bl = W2Tlo + ((size_t)r * DOUT + w * 32 + l15) * DH + l4 * 8;
    f32x4 acc[4][2];
    #pragma unroll
    for (int m = 0; m < 4; ++m) { acc[m][0] = (f32x4){0.f,0.f,0.f,0.f}; acc[m][1] = (f32x4){0.f,0.f,0.f,0.f}; }
    for (int kc = 0; kc < 4; ++kc) {
        if (kc) __syncthreads();
        {
            int row = tid >> 2, seg = tid & 3;
            const uint4* ph = (const uint4*)(hhi + (size_t)srcS[row] * DH + kc * 128 + seg * 32);
            const uint4* pl = (const uint4*)(hlo + (size_t)srcS[row] * DH + kc * 128 + seg * 32);
            unsigned rb = row * 256, sw = (row & 7) << 4;
            #pragma unroll
            for (int i = 0; i < 4; ++i) {
                unsigned off = (rb + seg * 64 + i * 16) ^ sw;
                *(uint4*)((char*)Ah + off) = ph[i];
                *(uint4*)((char*)Al + off) = pl[i];
            }
        }
        __syncthreads();
        bf16x8 ah[4][4], al[4][4];
        #pragma unroll
        for (int m = 0; m < 4; ++m) {
            int row = m * 16 + l15;
            unsigned rb = row * 256, sw = (row & 7) << 4;
            #pragma unroll
            for (int k = 0; k < 4; ++k) {
                unsigned off = (rb + k * 64 + l4 * 16) ^ sw;
                ah[m][k] = *(const bf16x8*)((const char*)Ah + off);
                al[m][k] = *(const bf16x8*)((const char*)Al + off);
            }
        }
        #pragma unroll
        for (int n = 0; n < 2; ++n) {
            #pragma unroll
            for (int k = 0; k < 4; ++k) {
                bf16x8 bh = *(const bf16x8*)(Bh + (size_t)n * 16 * DH + kc * 128 + k * 32);
                bf16x8 bl = *(const bf16x8*)(Bl + (size_t)n * 16 * DH + kc * 128 + k * 32);
                #pragma unroll
                for (int m = 0; m < 4; ++m) {
                    acc[m][n] = __builtin_amdgcn_mfma_f32_16x16x32_bf16(ah[m][k], bh, acc[m][n], 0, 0, 0);
                    acc[m][n] = __builtin_amdgcn_mfma_f32_16x16x32_bf16(ah[m][k], bl, acc[m][n], 0, 0, 0);
                    acc[m][n] = __builtin_amdgcn_mfma_f32_16x16x32_bf16(al[m][k], bh, acc[m][n], 0, 0, 0);
                }
            }
        }
    }
    float* mb = msg2 + (size_t)(start - cstart) * DOUT + w * 32;
    #pragma unroll
    for (int m = 0; m < 4; ++m) {
        int row0 = m * 16 + l4 * 4;
        #pragma unroll
        for (int rg = 0; rg < 4; ++rg) {
            int row = row0 + rg;
            if (row < cnt) {
                float* mp = mb + (size_t)row * DOUT;
                mp[l15] = acc[m][0][rg];
                mp[16 + l15] = acc[m][1][rg];
            }
        }
    }
}

// ---------------- layer2 agg: 2 waves per dst ----------------
__global__ void l2_agg_kernel(const float* __restrict__ msg2, const float* __restrict__ e2,
                              const int* __restrict__ dlist, const int* __restrict__ dedge,
                              const int* __restrict__ doffs, const int* __restrict__ boffs,
                              int c, float* __restrict__ zacc) {
    int tid = threadIdx.x;
    int w = tid >> 6, lane = tid & 63;
    int dl = blockIdx.x * 2 + (w >> 1);
    if (dl >= CHD) return;
    int d = c * CHD + dl;
    if (d >= NN) return;
    int q = w & 1;
    int lo_ = doffs[d], hi_ = doffs[d + 1];
    int cstart = boffs[c * NR];
    int col = q * 64 + lane;
    float a0 = 0.f, se = 0.f;
    for (int p = lo_; p < hi_; ++p) {
        float wgt = e2[dedge[p]];
        se += wgt;
        a0 += wgt * msg2[(size_t)(dlist[p] - cstart) * DOUT + col];
    }
    zacc[(size_t)d * DOUT + col] = a0 / (se + 1e-16f);
}

// ---------------- link-prediction decoder ----------------
__global__ void decode_kernel(const float* __restrict__ z, const int* __restrict__ tgt,
                              const float* __restrict__ lw1, const float* __restrict__ lb1,
                              const float* __restrict__ lw2, const float* __restrict__ lb2,
                              float* __restrict__ out) {
    __shared__ float Zt[TILE][129];
    __shared__ float red[TILE][17];
    int t0 = blockIdx.x * TILE;
    int tid = threadIdx.x;
    int cnt = NT - t0; if (cnt > TILE) cnt = TILE;
    int to = tid >> 4, te = tid & 15;
    float acc[4][8] = {};
    for (int kc = 0; kc < 2; ++kc) {
        if (kc) __syncthreads();
        for (int idx = tid; idx < TILE * 128; idx += 256) {
            int row = idx >> 7, i = idx & 127;
            float v = 0.f;
            if (row < cnt) {
                int node = tgt[kc * NT + t0 + row];
                v = z[(size_t)node * DOUT + i];
            }
            Zt[row][i] = v;
        }
        __syncthreads();
        const float* Wp = lw1 + (size_t)(kc * 128) * DOUT + to * 8;
        for (int i = 0; i < 128; ++i) {
            const float* wr = Wp + (size_t)i * DOUT;
            float4 w0 = *(const float4*)(wr);
            float4 w1 = *(const float4*)(wr + 4);
            float w[8] = {w0.x, w0.y, w0.z, w0.w, w1.x, w1.y, w1.z, w1.w};
            #pragma unroll
            for (int a = 0; a < 4; ++a) {
                float xv = Zt[te * 4 + a][i];
                #pragma unroll
                for (int b = 0; b < 8; ++b) acc[a][b] += xv * w[b];
            }
        }
    }
    float lb[8], lw[8];
    #pragma unroll
    for (int b = 0; b < 8; ++b) { lb[b] = lb1[to * 8 + b]; lw[b] = lw2[to * 8 + b]; }
    __syncthreads();
    #pragma unroll
    for (int a = 0; a < 4; ++a) {
        float s = 0.f;
        #pragma unroll
        for (int b = 0; b < 8; ++b) {
            float hv = acc[a][b] + lb[b];
            hv = hv > 0.f ? hv : 0.f;
            s += hv * lw[b];
        }
        red[te * 4 + a][to] = s;
    }
    __syncthreads();
    if (tid < cnt) {
        float s = 0.f;
        #pragma unroll
        for (int g = 0; g < 16; ++g) s += red[tid][g];
        out[t0 + tid] = s + lb2[0];
    }
}

extern "C" void kernel_launch(void* const* d_in, const int* in_sizes, int n_in,
                              void* d_out, int out_size, void* d_ws, size_t ws_size,
                              hipStream_t stream) {
    const float* x   = (const float*)d_in[0];
    const int*   ei  = (const int*)d_in[1];
    const int*   et  = (const int*)d_in[2];
    const int*   tgt = (const int*)d_in[3];
    const float* W1  = (const float*)d_in[4];
    const float* aq1 = (const float*)d_in[5];
    const float* ak1 = (const float*)d_in[6];
    const float* W2  = (const float*)d_in[7];
    const float* aq2 = (const float*)d_in[8];
    const float* ak2 = (const float*)d_in[9];
    const float* lw1 = (const float*)d_in[10];
    const float* lb1 = (const float*)d_in[11];
    const float* lw2 = (const float*)d_in[12];
    const float* lb2 = (const float*)d_in[13];
    float* out = (float*)d_out;
    (void)in_sizes; (void)n_in; (void)out_size; (void)ws_size;

    char* ws = (char*)d_ws;
    size_t off = 0;
    auto alloc = [&](size_t bytes) -> void* {
        void* p = ws + off;
        off += (bytes + 255) & ~(size_t)255;
        return p;
    };
    // zero-init block: histograms only
    int* cnt   = (int*)alloc(NBUCKET * sizeof(int));
    int* cnt_d = (int*)alloc((size_t)NN * sizeof(int));
    size_t zero_bytes = off;
    // no-init scratch
    int*   boffs    = (int*)alloc((NBUCKET + 1) * sizeof(int));
    int*   cursor   = (int*)alloc(NBUCKET * sizeof(int));
    int*   cts      = (int*)alloc((CHUNKS + 1) * sizeof(int));
    int*   doffs    = (int*)alloc((size_t)(NN + 1) * sizeof(int));
    int*   cursor_d = (int*)alloc((size_t)NN * sizeof(int));
    int*   border   = (int*)alloc((size_t)NE * sizeof(int));
    int*   dlist    = (int*)alloc((size_t)NE * sizeof(int));
    int*   dedge    = (int*)alloc((size_t)NE * sizeof(int));
    int*   tile_b   = (int*)alloc((size_t)NTILESMAX * sizeof(int));
    int*   tile_s   = (int*)alloc((size_t)NTILESMAX * sizeof(int));
    float* alpha1   = (float*)alloc((size_t)128 * 256 * 4);
    float* alpha2   = (float*)alloc((size_t)512 * 32 * 4);
    float* qk1      = (float*)alloc((size_t)NN * 256 * 4);
    float* qk2v     = (float*)alloc((size_t)NN * 32 * 4);
    float* e1       = (float*)alloc((size_t)NE * 8 * 4);
    float* e2       = (float*)alloc((size_t)NE * 4);
    float* zacc     = (float*)alloc((size_t)NN * DOUT * 4);
    unsigned short* xhi   = (unsigned short*)alloc((size_t)NN * DIN * 2);
    unsigned short* xlo   = (unsigned short*)alloc((size_t)NN * DIN * 2);
    unsigned short* hhi   = (unsigned short*)alloc((size_t)NN * DH * 2);
    unsigned short* hlo   = (unsigned short*)alloc((size_t)NN * DH * 2);
    unsigned short* W1Thi = (unsigned short*)alloc((size_t)NR * DH * DIN * 2);
    unsigned short* W1Tlo = (unsigned short*)alloc((size_t)NR * DH * DIN * 2);
    unsigned short* W2Thi = (unsigned short*)alloc((size_t)NR * DOUT * DH * 2);
    unsigned short* W2Tlo = (unsigned short*)alloc((size_t)NR * DOUT * DH * 2);
    float* msg      = (float*)alloc((size_t)MSGROWS * DH * 4);   // reused as msg2

    hipMemsetAsync(ws, 0, zero_bytes, stream);
    alpha1_kernel<<<DIN, 256, 0, stream>>>(W1, aq1, ak1, alpha1);
    alpha2_kernel<<<(DH * 32 + 255) / 256, 256, 0, stream>>>(W2, aq2, ak2, alpha2);
    split_x_kernel<<<(NN * DIN / 4 + 255) / 256, 256, 0, stream>>>(x, xhi, xlo);
    splitW1T_kernel<<<NR * 8, 256, 0, stream>>>(W1, W1Thi, W1Tlo);
    splitW2T_kernel<<<NR * 2, 256, 0, stream>>>(W2, W2Thi, W2Tlo);
    hist_kernel<<<(NE + 255) / 256, 256, 0, stream>>>(ei, et, cnt, cnt_d);
    scan_bkt_kernel<<<1, 64, 0, stream>>>(cnt, boffs, cursor, cts);
    tilemap_kernel<<<(NTILESMAX + 255) / 256, 256, 0, stream>>>(boffs, tile_b, tile_s);
    bucket_place_kernel<<<(NE + 255) / 256, 256, 0, stream>>>(ei, et, cursor, border);
    scan_dst_kernel<<<1, 1024, 0, stream>>>(cnt_d, doffs, cursor_d);
    place_dst_kernel<<<(NE + 255) / 256, 256, 0, stream>>>(border, ei, cursor_d, dlist, dedge);
    qk1_kernel<<<(NN + TILE - 1) / TILE, 256, 0, stream>>>(x, alpha1, qk1);
    elogit1_kernel<<<(NE + 255) / 256, 256, 0, stream>>>(ei, et, qk1, e1);
    for (int c = 0; c < CHUNKS; ++c) {
        l1_gemm_kernel<<<MAXTPC, 256, 0, stream>>>(xhi, xlo, W1Thi, W1Tlo, ei, border,
                                                   tile_b, tile_s, boffs, cts, c, msg);
        l1_agg_kernel<<<CHD, 256, 0, stream>>>(msg, e1, dlist, dedge, doffs, boffs, c, hhi, hlo);
    }
    qk2_kernel<<<(NN + TILE - 1) / TILE, 256, 0, stream>>>(hhi, hlo, alpha2, qk2v);
    elogit2_kernel<<<(NE + 255) / 256, 256, 0, stream>>>(ei, et, qk2v, e2);
    for (int c = 0; c < CHUNKS; ++c) {
        l2_gemm_kernel<<<MAXTPC, 256, 0, stream>>>(hhi, hlo, W2Thi, W2Tlo, ei, border,
                                                   tile_b, tile_s, boffs, cts, c, msg);
        l2_agg_kernel<<<(CHD + 1) / 2, 256, 0, stream>>>(msg, e2, dlist, dedge, doffs, boffs, c, zacc);
    }
    decode_kernel<<<(NT + TILE - 1) / TILE, 256, 0, stream>>>(zacc, tgt, lw1, lb1, lw2, lb2, out);
}

// Round 4
// 1351.747 us; speedup vs baseline: 4.8179x; 1.8256x over previous
//
#include <hip/hip_runtime.h>
#include <cstdint>
#include <cstddef>

#define NN     20000
#define NE     320000
#define NR     16
#define DIN    128
#define DH     512
#define DOUT   128
#define NT     50000
#define TILE   64
#define CHUNKS 8
#define CHD    2500
#define NBUCKET (CHUNKS * NR)          // 128
#define MSGROWS 46080                  // max edges per chunk (40000 avg + margin)
#define MAXTPC  768                    // max GEMM tiles per chunk
#define NTILESMAX (NE / TILE + NBUCKET)

typedef __attribute__((ext_vector_type(8))) short bf16x8;
typedef __attribute__((ext_vector_type(4))) float f32x4;

__device__ __forceinline__ unsigned short f2bf(float x) {
    unsigned int b = __float_as_uint(x);
    b = b + 0x7fffu + ((b >> 16) & 1u);
    return (unsigned short)(b >> 16);
}
__device__ __forceinline__ float bf2f(unsigned short u) {
    return __uint_as_float(((unsigned int)u) << 16);
}
__device__ __forceinline__ unsigned packbf(float lo, float hi) {
    return (unsigned)f2bf(lo) | ((unsigned)f2bf(hi) << 16);
}

// ---------------- fold attention vectors into weights ----------------
__global__ void alpha1_kernel(const float* __restrict__ W1, const float* __restrict__ aq1,
                              const float* __restrict__ ak1, float* __restrict__ alpha1) {
    int i = blockIdx.x;            // 0..127
    int c = threadIdx.x;           // 0..255
    int r = c >> 4, s = (c >> 3) & 1, h = c & 7;
    const float* att = (s == 0 ? aq1 : ak1) + (r * 8 + h) * 64;
    const float* w = W1 + ((size_t)(r * DIN + i)) * DH + h * 64;
    float acc = 0.f;
    #pragma unroll 8
    for (int o = 0; o < 64; ++o) acc += w[o] * att[o];
    alpha1[i * 256 + c] = acc;
}

__global__ void alpha2_kernel(const float* __restrict__ W2, const float* __restrict__ aq2,
                              const float* __restrict__ ak2, float* __restrict__ alpha2) {
    int g = blockIdx.x * blockDim.x + threadIdx.x;
    if (g >= DH * 32) return;
    int i = g >> 5, c = g & 31;
    int r = c >> 1, s = c & 1;
    const float* att = (s == 0 ? aq2 : ak2) + r * DOUT;
    const float* w = W2 + ((size_t)(r * DH + i)) * DOUT;
    float acc = 0.f;
    #pragma unroll 8
    for (int o = 0; o < DOUT; ++o) acc += w[o] * att[o];
    alpha2[i * 32 + c] = acc;
}

// W1 [16][128][512] -> W1T hi/lo [16][512][128]
__global__ void splitW1T_kernel(const float* __restrict__ W1, unsigned short* __restrict__ Whi,
                                unsigned short* __restrict__ Wlo) {
    __shared__ float T[128 * 65];
    int r = blockIdx.x >> 3;
    int ob = blockIdx.x & 7;
    int tid = threadIdx.x;
    for (int idx = tid; idx < 128 * 64; idx += 256) {
        int i = idx >> 6, o = idx & 63;
        T[i * 65 + o] = W1[((size_t)(r * DIN + i)) * DH + ob * 64 + o];
    }
    __syncthreads();
    for (int idx = tid; idx < 64 * 128; idx += 256) {
        int o = idx >> 7, i = idx & 127;
        float v = T[i * 65 + o];
        unsigned short h = f2bf(v);
        size_t off = ((size_t)r * DH + ob * 64 + o) * DIN + i;
        Whi[off] = h;
        Wlo[off] = f2bf(v - bf2f(h));
    }
}

// W2 [16][512][128] -> W2T hi/lo [16][128][512]
__global__ void splitW2T_kernel(const float* __restrict__ W2, unsigned short* __restrict__ Whi,
                                unsigned short* __restrict__ Wlo) {
    __shared__ float T[128 * 65];
    int r = blockIdx.x >> 1;
    int ob = blockIdx.x & 1;
    int tid = threadIdx.x;
    for (int kc = 0; kc < 4; ++kc) {
        if (kc) __syncthreads();
        for (int idx = tid; idx < 128 * 64; idx += 256) {
            int k = idx >> 6, o = idx & 63;
            T[k * 65 + o] = W2[((size_t)(r * DH + kc * 128 + k)) * DOUT + ob * 64 + o];
        }
        __syncthreads();
        for (int idx = tid; idx < 64 * 128; idx += 256) {
            int o = idx >> 7, k = idx & 127;
            float v = T[k * 65 + o];
            unsigned short h = f2bf(v);
            size_t off = ((size_t)r * DOUT + ob * 64 + o) * DH + kc * 128 + k;
            Whi[off] = h;
            Wlo[off] = f2bf(v - bf2f(h));
        }
    }
}

// ---------------- sorts ----------------
__global__ void hist_kernel(const int* __restrict__ ei, const int* __restrict__ et,
                            int* __restrict__ cnt, int* __restrict__ cnt_d) {
    __shared__ int bins[NBUCKET];
    int t = threadIdx.x;
    if (t < NBUCKET) bins[t] = 0;
    __syncthreads();
    int e = blockIdx.x * 256 + t;
    if (e < NE) {
        int d = ei[NE + e];
        int key = (d / CHD) * NR + et[e];
        atomicAdd(&bins[key], 1);
        atomicAdd(&cnt_d[d], 1);
    }
    __syncthreads();
    if (t < NBUCKET && bins[t]) atomicAdd(&cnt[t], bins[t]);
}

__global__ void scan_bkt_kernel(const int* __restrict__ cnt, int* __restrict__ boffs,
                                int* __restrict__ cursor, int* __restrict__ cts) {
    if (threadIdx.x != 0) return;
    int acc = 0, tiles = 0;
    for (int b = 0; b < NBUCKET; ++b) {
        if ((b & (NR - 1)) == 0) cts[b >> 4] = tiles;
        boffs[b] = acc; cursor[b] = acc;
        int cn = cnt[b];
        tiles += (cn + TILE - 1) / TILE;
        acc += cn;
    }
    boffs[NBUCKET] = acc; cts[CHUNKS] = tiles;
}

__global__ void tilemap_kernel(const int* __restrict__ boffs, int* __restrict__ tile_b,
                               int* __restrict__ tile_s) {
    __shared__ int bo[NBUCKET + 1];
    int tid = threadIdx.x;
    if (tid <= NBUCKET) bo[tid] = boffs[tid];
    __syncthreads();
    int t = blockIdx.x * 256 + tid;
    if (t >= NTILESMAX) return;
    int acc = 0, bb = -1, ss = 0;
    for (int b = 0; b < NBUCKET; ++b) {
        int cn = bo[b + 1] - bo[b];
        int nt = (cn + TILE - 1) / TILE;
        if (t >= acc && t < acc + nt) { bb = b; ss = bo[b] + (t - acc) * TILE; }
        acc += nt;
    }
    tile_b[t] = bb; tile_s[t] = ss;
}

__global__ void bucket_place_kernel(const int* __restrict__ ei, const int* __restrict__ et,
                                    int* __restrict__ cursor, int* __restrict__ border) {
    __shared__ int binc[NBUCKET], base_[NBUCKET], rank_[NBUCKET];
    int t = threadIdx.x;
    if (t < NBUCKET) { binc[t] = 0; rank_[t] = 0; }
    __syncthreads();
    int e = blockIdx.x * 256 + t;
    int key = -1;
    if (e < NE) { key = (ei[NE + e] / CHD) * NR + et[e]; atomicAdd(&binc[key], 1); }
    __syncthreads();
    if (t < NBUCKET && binc[t]) base_[t] = atomicAdd(&cursor[t], binc[t]);
    __syncthreads();
    if (key >= 0) border[base_[key] + atomicAdd(&rank_[key], 1)] = e;
}

__global__ void scan_dst_kernel(const int* __restrict__ cnt_d, int* __restrict__ doffs,
                                int* __restrict__ cursor_d) {
    __shared__ int part[1024];
    int t = threadIdx.x;
    int base = t * 20;
    int s = 0;
    for (int i = 0; i < 20 && base + i < NN; ++i) s += cnt_d[base + i];
    part[t] = s;
    __syncthreads();
    for (int off = 1; off < 1024; off <<= 1) {
        int v = (t >= off) ? part[t - off] : 0;
        __syncthreads();
        part[t] += v;
        __syncthreads();
    }
    int run = part[t] - s;
    for (int i = 0; i < 20 && base + i < NN; ++i) {
        doffs[base + i] = run; cursor_d[base + i] = run;
        run += cnt_d[base + i];
    }
    if (t == 1023) doffs[NN] = part[1023];
}

__global__ void place_dst_kernel(const int* __restrict__ border, const int* __restrict__ ei,
                                 int* __restrict__ cursor_d, int* __restrict__ dlist,
                                 int* __restrict__ dedge) {
    int pos = blockIdx.x * 256 + threadIdx.x;
    if (pos >= NE) return;
    int e = border[pos];
    int d = ei[NE + e];
    int idx = atomicAdd(&cursor_d[d], 1);
    dlist[idx] = pos;
    dedge[idx] = e;
}

// ---------------- qk1 = x @ alpha1  ([N,128] @ [128,256]) ----------------
__global__ void qk1_kernel(const float* __restrict__ x, const float* __restrict__ alpha1,
                           float* __restrict__ qk1) {
    __shared__ float Xt[TILE][DIN + 1];
    int n0 = blockIdx.x * TILE;
    int tid = threadIdx.x;
    for (int idx = tid; idx < TILE * DIN; idx += 256) {
        int row = idx >> 7, i = idx & 127;
        int n = n0 + row;
        Xt[row][i] = (n < NN) ? x[(size_t)n * DIN + i] : 0.f;
    }
    __syncthreads();
    int to = tid >> 4, te = tid & 15;
    for (int c = 0; c < 2; ++c) {
        float acc[4][8] = {};
        const float* Wp = alpha1 + c * 128 + to * 8;
        for (int i = 0; i < DIN; ++i) {
            float4 w0 = *(const float4*)(Wp + (size_t)i * 256);
            float4 w1 = *(const float4*)(Wp + (size_t)i * 256 + 4);
            float w[8] = {w0.x, w0.y, w0.z, w0.w, w1.x, w1.y, w1.z, w1.w};
            #pragma unroll
            for (int a = 0; a < 4; ++a) {
                float xv = Xt[te * 4 + a][i];
                #pragma unroll
                for (int b = 0; b < 8; ++b) acc[a][b] += xv * w[b];
            }
        }
        #pragma unroll
        for (int a = 0; a < 4; ++a) {
            int n = n0 + te * 4 + a;
            if (n < NN) {
                float* op = qk1 + (size_t)n * 256 + c * 128 + to * 8;
                #pragma unroll
                for (int b = 0; b < 8; ++b) op[b] = acc[a][b];
            }
        }
    }
}

__global__ void elogit1_kernel(const int* __restrict__ ei, const int* __restrict__ et,
                               const float* __restrict__ qk1, float* __restrict__ e1) {
    int e = blockIdx.x * blockDim.x + threadIdx.x;
    if (e >= NE) return;
    int src = ei[e], dst = ei[NE + e], r = et[e];
    const float* qp = qk1 + (size_t)dst * 256 + r * 16;
    const float* kp = qk1 + (size_t)src * 256 + r * 16 + 8;
    float* ep = e1 + (size_t)e * 8;
    #pragma unroll
    for (int h = 0; h < 8; ++h) {
        float l = qp[h] + kp[h];
        l = l > 0.f ? l : 0.2f * l;
        ep[h] = __expf(l);
    }
}

// ---------------- layer1 GEMM (MFMA, split bf16): msg (packed bf16) ----------------
// msg physical layout per row: u32[256]; slot = w*64 + q*16 + l15 holds
// cols (w*128 + n0*16 + l15, +32) as 2xbf16, n0 = (q>>1)*4 + (q&1).
__global__ __launch_bounds__(256, 2)
void l1_gemm_kernel(const float* __restrict__ x,
                    const unsigned short* __restrict__ W1Thi, const unsigned short* __restrict__ W1Tlo,
                    const int* __restrict__ ei, const int* __restrict__ border,
                    const int* __restrict__ tile_b, const int* __restrict__ tile_s,
                    const int* __restrict__ boffs, const int* __restrict__ cts,
                    int c, unsigned* __restrict__ msgu) {
    int t = cts[c] + blockIdx.x;
    if (t >= cts[c + 1]) return;
    int b = tile_b[t];
    int r = b & (NR - 1);
    int start = tile_s[t];
    int cstart = boffs[c * NR];
    int cnt = boffs[b + 1] - start; if (cnt > TILE) cnt = TILE;
    __shared__ __align__(16) unsigned short Ah[64 * 128];
    __shared__ __align__(16) unsigned short Al[64 * 128];
    __shared__ int srcS[TILE];
    int tid = threadIdx.x;
    if (tid < TILE) {
        int sv = 0;
        if (tid < cnt) { int e = border[start + tid]; sv = ei[e]; }
        srcS[tid] = sv;
    }
    __syncthreads();
    {
        int row = tid >> 2, seg = tid & 3;
        const float4* px = (const float4*)(x + (size_t)srcS[row] * DIN + seg * 32);
        unsigned rb = row * 256, sw = (row & 7) << 4;
        #pragma unroll
        for (int g = 0; g < 4; ++g) {
            float4 a = px[g * 2], bq = px[g * 2 + 1];
            unsigned short h0 = f2bf(a.x), h1 = f2bf(a.y), h2 = f2bf(a.z), h3 = f2bf(a.w);
            unsigned short h4 = f2bf(bq.x), h5 = f2bf(bq.y), h6 = f2bf(bq.z), h7 = f2bf(bq.w);
            uint4 uh, ul;
            uh.x = (unsigned)h0 | ((unsigned)h1 << 16);
            uh.y = (unsigned)h2 | ((unsigned)h3 << 16);
            uh.z = (unsigned)h4 | ((unsigned)h5 << 16);
            uh.w = (unsigned)h6 | ((unsigned)h7 << 16);
            ul.x = (unsigned)f2bf(a.x - bf2f(h0)) | ((unsigned)f2bf(a.y - bf2f(h1)) << 16);
            ul.y = (unsigned)f2bf(a.z - bf2f(h2)) | ((unsigned)f2bf(a.w - bf2f(h3)) << 16);
            ul.z = (unsigned)f2bf(bq.x - bf2f(h4)) | ((unsigned)f2bf(bq.y - bf2f(h5)) << 16);
            ul.w = (unsigned)f2bf(bq.z - bf2f(h6)) | ((unsigned)f2bf(bq.w - bf2f(h7)) << 16);
            unsigned off = (rb + seg * 64 + g * 16) ^ sw;
            *(uint4*)((char*)Ah + off) = uh;
            *(uint4*)((char*)Al + off) = ul;
        }
    }
    __syncthreads();
    int w = tid >> 6, lane = tid & 63;
    int l15 = lane & 15, l4 = lane >> 4;
    const unsigned short* Bh = W1Thi + ((size_t)r * DH + w * 128 + l15) * DIN + l4 * 8;
    const unsigned short* Bl = W1Tlo + ((size_t)r * DH + w * 128 + l15) * DIN + l4 * 8;
    f32x4 acc[4][8];
    #pragma unroll
    for (int m = 0; m < 4; ++m)
        #pragma unroll
        for (int n = 0; n < 8; ++n) acc[m][n] = (f32x4){0.f, 0.f, 0.f, 0.f};
    #pragma unroll
    for (int mg = 0; mg < 2; ++mg) {
        bf16x8 ah[2][4], al[2][4];
        #pragma unroll
        for (int mm = 0; mm < 2; ++mm) {
            int row = (mg * 2 + mm) * 16 + l15;
            unsigned rb = row * 256, sw = (row & 7) << 4;
            #pragma unroll
            for (int k = 0; k < 4; ++k) {
                unsigned off = (rb + k * 64 + l4 * 16) ^ sw;
                ah[mm][k] = *(const bf16x8*)((const char*)Ah + off);
                al[mm][k] = *(const bf16x8*)((const char*)Al + off);
            }
        }
        #pragma unroll
        for (int n = 0; n < 8; ++n) {
            #pragma unroll
            for (int k = 0; k < 4; ++k) {
                bf16x8 bh = *(const bf16x8*)(Bh + (size_t)n * 16 * DIN + k * 32);
                bf16x8 bl = *(const bf16x8*)(Bl + (size_t)n * 16 * DIN + k * 32);
                #pragma unroll
                for (int mm = 0; mm < 2; ++mm) {
                    int m = mg * 2 + mm;
                    acc[m][n] = __builtin_amdgcn_mfma_f32_16x16x32_bf16(ah[mm][k], bh, acc[m][n], 0, 0, 0);
                    acc[m][n] = __builtin_amdgcn_mfma_f32_16x16x32_bf16(ah[mm][k], bl, acc[m][n], 0, 0, 0);
                    acc[m][n] = __builtin_amdgcn_mfma_f32_16x16x32_bf16(al[mm][k], bh, acc[m][n], 0, 0, 0);
                }
            }
        }
    }
    unsigned* mb = msgu + (size_t)(start - cstart) * 256 + w * 64 + l15;
    #pragma unroll
    for (int m = 0; m < 4; ++m) {
        int row0 = m * 16 + l4 * 4;
        #pragma unroll
        for (int rg = 0; rg < 4; ++rg) {
            int row = row0 + rg;
            if (row < cnt) {
                unsigned* mp = mb + (size_t)row * 256;
                #pragma unroll
                for (int q = 0; q < 4; ++q) {
                    int n0 = ((q >> 1) << 2) | (q & 1);
                    mp[q * 16] = packbf(acc[m][n0][rg], acc[m][n0 + 2][rg]);
                }
            }
        }
    }
}

// ---------------- layer1 agg: block per dst, 256 threads = 256 u32 slots ----------------
__global__ void l1_agg_kernel(const unsigned* __restrict__ msgu, const float* __restrict__ e1,
                              const int* __restrict__ dlist, const int* __restrict__ dedge,
                              const int* __restrict__ doffs, const int* __restrict__ boffs,
                              int c, float* __restrict__ h) {
    int tid = threadIdx.x;
    int d = c * CHD + blockIdx.x;
    if (d >= NN) return;
    int lo_ = doffs[d], hi_ = doffs[d + 1];
    int cstart = boffs[c * NR];
    int head = tid >> 5;
    float a0 = 0.f, a1 = 0.f, se = 0.f;
    for (int p = lo_; p < hi_; ++p) {
        int pos = dlist[p];
        float wgt = e1[(size_t)dedge[p] * 8 + head];
        se += wgt;
        unsigned v = msgu[(size_t)(pos - cstart) * 256 + tid];
        a0 += wgt * bf2f((unsigned short)(v & 0xffff));
        a1 += wgt * bf2f((unsigned short)(v >> 16));
    }
    float inv = 1.f / (se + 1e-16f);
    a0 *= inv; a1 *= inv;
    a0 = a0 > 0.f ? a0 : 0.f;
    a1 = a1 > 0.f ? a1 : 0.f;
    int w = tid >> 6, q = (tid >> 4) & 3, l15 = tid & 15;
    int n0 = ((q >> 1) << 2) | (q & 1);
    int c0 = w * 128 + n0 * 16 + l15;
    h[(size_t)d * DH + c0] = a0;
    h[(size_t)d * DH + c0 + 32] = a1;
}

// ---------------- qk2 = h @ alpha2  ([N,512] @ [512,32]) ----------------
__global__ void qk2_kernel(const float* __restrict__ h, const float* __restrict__ alpha2,
                           float* __restrict__ qk2) {
    __shared__ float Ht[TILE][129];
    int n0 = blockIdx.x * TILE;
    int tid = threadIdx.x;
    int to = tid >> 4, te = tid & 15;
    float acc[4][2] = {};
    for (int kc = 0; kc < 4; ++kc) {
        __syncthreads();
        for (int idx = tid; idx < TILE * 128; idx += 256) {
            int row = idx >> 7, i = idx & 127;
            int n = n0 + row;
            Ht[row][i] = (n < NN) ? h[(size_t)n * DH + kc * 128 + i] : 0.f;
        }
        __syncthreads();
        const float* Wp = alpha2 + (size_t)(kc * 128) * 32 + to * 2;
        for (int i = 0; i < 128; ++i) {
            float2 w = *(const float2*)(Wp + (size_t)i * 32);
            #pragma unroll
            for (int a = 0; a < 4; ++a) {
                float xv = Ht[te * 4 + a][i];
                acc[a][0] += xv * w.x; acc[a][1] += xv * w.y;
            }
        }
    }
    #pragma unroll
    for (int a = 0; a < 4; ++a) {
        int n = n0 + te * 4 + a;
        if (n < NN) {
            float2 o2; o2.x = acc[a][0]; o2.y = acc[a][1];
            *(float2*)(qk2 + (size_t)n * 32 + to * 2) = o2;
        }
    }
}

__global__ void elogit2_kernel(const int* __restrict__ ei, const int* __restrict__ et,
                               const float* __restrict__ qk2, float* __restrict__ e2) {
    int e = blockIdx.x * blockDim.x + threadIdx.x;
    if (e >= NE) return;
    int src = ei[e], dst = ei[NE + e], r = et[e];
    float l = qk2[(size_t)dst * 32 + r * 2] + qk2[(size_t)src * 32 + r * 2 + 1];
    l = l > 0.f ? l : 0.2f * l;
    e2[e] = __expf(l);
}

// ---------------- layer2 GEMM (MFMA, split bf16): msg2 packed bf16 [rows][64 u32] ----------------
__global__ __launch_bounds__(256, 2)
void l2_gemm_kernel(const float* __restrict__ h,
                    const unsigned short* __restrict__ W2Thi, const unsigned short* __restrict__ W2Tlo,
                    const int* __restrict__ ei, const int* __restrict__ border,
                    const int* __restrict__ tile_b, const int* __restrict__ tile_s,
                    const int* __restrict__ boffs, const int* __restrict__ cts,
                    int c, unsigned* __restrict__ msgu2) {
    int t = cts[c] + blockIdx.x;
    if (t >= cts[c + 1]) return;
    int b = tile_b[t];
    int r = b & (NR - 1);
    int start = tile_s[t];
    int cstart = boffs[c * NR];
    int cnt = boffs[b + 1] - start; if (cnt > TILE) cnt = TILE;
    __shared__ __align__(16) unsigned short Ah[64 * 128];
    __shared__ __align__(16) unsigned short Al[64 * 128];
    __shared__ int srcS[TILE];
    int tid = threadIdx.x;
    if (tid < TILE) {
        int sv = 0;
        if (tid < cnt) { int e = border[start + tid]; sv = ei[e]; }
        srcS[tid] = sv;
    }
    __syncthreads();
    int w = tid >> 6, lane = tid & 63;
    int l15 = lane & 15, l4 = lane >> 4;
    const unsigned short* Bh = W2Thi + ((size_t)r * DOUT + w * 32 + l15) * DH + l4 * 8;
    const unsigned short* Bl = W2Tlo + ((size_t)r * DOUT + w * 32 + l15) * DH + l4 * 8;
    f32x4 acc[4][2];
    #pragma unroll
    for (int m = 0; m < 4; ++m) { acc[m][0] = (f32x4){0.f,0.f,0.f,0.f}; acc[m][1] = (f32x4){0.f,0.f,0.f,0.f}; }
    for (int kc = 0; kc < 4; ++kc) {
        if (kc) __syncthreads();
        {
            int row = tid >> 2, seg = tid & 3;
            const float4* px = (const float4*)(h + (size_t)srcS[row] * DH + kc * 128 + seg * 32);
            unsigned rb = row * 256, sw = (row & 7) << 4;
            #pragma unroll
            for (int g = 0; g < 4; ++g) {
                float4 a = px[g * 2], bq = px[g * 2 + 1];
                unsigned short h0 = f2bf(a.x), h1 = f2bf(a.y), h2 = f2bf(a.z), h3 = f2bf(a.w);
                unsigned short h4 = f2bf(bq.x), h5 = f2bf(bq.y), h6 = f2bf(bq.z), h7 = f2bf(bq.w);
                uint4 uh, ul;
                uh.x = (unsigned)h0 | ((unsigned)h1 << 16);
                uh.y = (unsigned)h2 | ((unsigned)h3 << 16);
                uh.z = (unsigned)h4 | ((unsigned)h5 << 16);
                uh.w = (unsigned)h6 | ((unsigned)h7 << 16);
                ul.x = (unsigned)f2bf(a.x - bf2f(h0)) | ((unsigned)f2bf(a.y - bf2f(h1)) << 16);
                ul.y = (unsigned)f2bf(a.z - bf2f(h2)) | ((unsigned)f2bf(a.w - bf2f(h3)) << 16);
                ul.z = (unsigned)f2bf(bq.x - bf2f(h4)) | ((unsigned)f2bf(bq.y - bf2f(h5)) << 16);
                ul.w = (unsigned)f2bf(bq.z - bf2f(h6)) | ((unsigned)f2bf(bq.w - bf2f(h7)) << 16);
                unsigned off = (rb + seg * 64 + g * 16) ^ sw;
                *(uint4*)((char*)Ah + off) = uh;
                *(uint4*)((char*)Al + off) = ul;
            }
        }
        __syncthreads();
        bf16x8 ah[4][4], al[4][4];
        #pragma unroll
        for (int m = 0; m < 4; ++m) {
            int row = m * 16 + l15;
            unsigned rb = row * 256, sw = (row & 7) << 4;
            #pragma unroll
            for (int k = 0; k < 4; ++k) {
                unsigned off = (rb + k * 64 + l4 * 16) ^ sw;
                ah[m][k] = *(const bf16x8*)((const char*)Ah + off);
                al[m][k] = *(const bf16x8*)((const char*)Al + off);
            }
        }
        #pragma unroll
        for (int n = 0; n < 2; ++n) {
            #pragma unroll
            for (int k = 0; k < 4; ++k) {
                bf16x8 bh = *(const bf16x8*)(Bh + (size_t)n * 16 * DH + kc * 128 + k * 32);
                bf16x8 bl = *(const bf16x8*)(Bl + (size_t)n * 16 * DH + kc * 128 + k * 32);
                #pragma unroll
                for (int m = 0; m < 4; ++m) {
                    acc[m][n] = __builtin_amdgcn_mfma_f32_16x16x32_bf16(ah[m][k], bh, acc[m][n], 0, 0, 0);
                    acc[m][n] = __builtin_amdgcn_mfma_f32_16x16x32_bf16(ah[m][k], bl, acc[m][n], 0, 0, 0);
                    acc[m][n] = __builtin_amdgcn_mfma_f32_16x16x32_bf16(al[m][k], bh, acc[m][n], 0, 0, 0);
                }
            }
        }
    }
    // pack cols (w*32+l15, +16) into u32 slot w*16+l15
    unsigned* mb = msgu2 + (size_t)(start - cstart) * 64 + w * 16 + l15;
    #pragma unroll
    for (int m = 0; m < 4; ++m) {
        int row0 = m * 16 + l4 * 4;
        #pragma unroll
        for (int rg = 0; rg < 4; ++rg) {
            int row = row0 + rg;
            if (row < cnt) {
                mb[(size_t)row * 64] = packbf(acc[m][0][rg], acc[m][1][rg]);
            }
        }
    }
}

// ---------------- layer2 agg: 4 dsts per block, 1 wave per dst ----------------
__global__ void l2_agg_kernel(const unsigned* __restrict__ msgu2, const float* __restrict__ e2,
                              const int* __restrict__ dlist, const int* __restrict__ dedge,
                              const int* __restrict__ doffs, const int* __restrict__ boffs,
                              int c, float* __restrict__ zacc) {
    int tid = threadIdx.x;
    int dl = blockIdx.x * 4 + (tid >> 6);
    if (dl >= CHD) return;
    int d = c * CHD + dl;
    if (d >= NN) return;
    int slot = tid & 63;
    int lo_ = doffs[d], hi_ = doffs[d + 1];
    int cstart = boffs[c * NR];
    float a0 = 0.f, a1 = 0.f, se = 0.f;
    for (int p = lo_; p < hi_; ++p) {
        float wgt = e2[dedge[p]];
        se += wgt;
        unsigned v = msgu2[(size_t)(dlist[p] - cstart) * 64 + slot];
        a0 += wgt * bf2f((unsigned short)(v & 0xffff));
        a1 += wgt * bf2f((unsigned short)(v >> 16));
    }
    float inv = 1.f / (se + 1e-16f);
    int w = slot >> 4, l15 = slot & 15;
    int c0 = w * 32 + l15;
    zacc[(size_t)d * DOUT + c0] = a0 * inv;
    zacc[(size_t)d * DOUT + c0 + 16] = a1 * inv;
}

// ---------------- link-prediction decoder ----------------
__global__ void decode_kernel(const float* __restrict__ z, const int* __restrict__ tgt,
                              const float* __restrict__ lw1, const float* __restrict__ lb1,
                              const float* __restrict__ lw2, const float* __restrict__ lb2,
                              float* __restrict__ out) {
    __shared__ float Zt[TILE][129];
    __shared__ float red[TILE][17];
    int t0 = blockIdx.x * TILE;
    int tid = threadIdx.x;
    int cnt = NT - t0; if (cnt > TILE) cnt = TILE;
    int to = tid >> 4, te = tid & 15;
    float acc[4][8] = {};
    for (int kc = 0; kc < 2; ++kc) {
        if (kc) __syncthreads();
        for (int idx = tid; idx < TILE * 128; idx += 256) {
            int row = idx >> 7, i = idx & 127;
            float v = 0.f;
            if (row < cnt) {
                int node = tgt[kc * NT + t0 + row];
                v = z[(size_t)node * DOUT + i];
            }
            Zt[row][i] = v;
        }
        __syncthreads();
        const float* Wp = lw1 + (size_t)(kc * 128) * DOUT + to * 8;
        for (int i = 0; i < 128; ++i) {
            const float* wr = Wp + (size_t)i * DOUT;
            float4 w0 = *(const float4*)(wr);
            float4 w1 = *(const float4*)(wr + 4);
            float w[8] = {w0.x, w0.y, w0.z, w0.w, w1.x, w1.y, w1.z, w1.w};
            #pragma unroll
            for (int a = 0; a < 4; ++a) {
                float xv = Zt[te * 4 + a][i];
                #pragma unroll
                for (int b = 0; b < 8; ++b) acc[a][b] += xv * w[b];
            }
        }
    }
    float lb[8], lw[8];
    #pragma unroll
    for (int b = 0; b < 8; ++b) { lb[b] = lb1[to * 8 + b]; lw[b] = lw2[to * 8 + b]; }
    __syncthreads();
    #pragma unroll
    for (int a = 0; a < 4; ++a) {
        float s = 0.f;
        #pragma unroll
        for (int b = 0; b < 8; ++b) {
            float hv = acc[a][b] + lb[b];
            hv = hv > 0.f ? hv : 0.f;
            s += hv * lw[b];
        }
        red[te * 4 + a][to] = s;
    }
    __syncthreads();
    if (tid < cnt) {
        float s = 0.f;
        #pragma unroll
        for (int g = 0; g < 16; ++g) s += red[tid][g];
        out[t0 + tid] = s + lb2[0];
    }
}

extern "C" void kernel_launch(void* const* d_in, const int* in_sizes, int n_in,
                              void* d_out, int out_size, void* d_ws, size_t ws_size,
                              hipStream_t stream) {
    const float* x   = (const float*)d_in[0];
    const int*   ei  = (const int*)d_in[1];
    const int*   et  = (const int*)d_in[2];
    const int*   tgt = (const int*)d_in[3];
    const float* W1  = (const float*)d_in[4];
    const float* aq1 = (const float*)d_in[5];
    const float* ak1 = (const float*)d_in[6];
    const float* W2  = (const float*)d_in[7];
    const float* aq2 = (const float*)d_in[8];
    const float* ak2 = (const float*)d_in[9];
    const float* lw1 = (const float*)d_in[10];
    const float* lb1 = (const float*)d_in[11];
    const float* lw2 = (const float*)d_in[12];
    const float* lb2 = (const float*)d_in[13];
    float* out = (float*)d_out;
    (void)in_sizes; (void)n_in; (void)out_size; (void)ws_size;

    char* ws = (char*)d_ws;
    size_t off = 0;
    auto alloc = [&](size_t bytes) -> void* {
        void* p = ws + off;
        off += (bytes + 255) & ~(size_t)255;
        return p;
    };
    // zero-init block: histograms only
    int* cnt   = (int*)alloc(NBUCKET * sizeof(int));
    int* cnt_d = (int*)alloc((size_t)NN * sizeof(int));
    size_t zero_bytes = off;
    // no-init scratch
    int*   boffs    = (int*)alloc((NBUCKET + 1) * sizeof(int));
    int*   cursor   = (int*)alloc(NBUCKET * sizeof(int));
    int*   cts      = (int*)alloc((CHUNKS + 1) * sizeof(int));
    int*   doffs    = (int*)alloc((size_t)(NN + 1) * sizeof(int));
    int*   cursor_d = (int*)alloc((size_t)NN * sizeof(int));
    int*   border   = (int*)alloc((size_t)NE * sizeof(int));
    int*   dlist    = (int*)alloc((size_t)NE * sizeof(int));
    int*   dedge    = (int*)alloc((size_t)NE * sizeof(int));
    int*   tile_b   = (int*)alloc((size_t)NTILESMAX * sizeof(int));
    int*   tile_s   = (int*)alloc((size_t)NTILESMAX * sizeof(int));
    float* alpha1   = (float*)alloc((size_t)128 * 256 * 4);
    float* alpha2   = (float*)alloc((size_t)512 * 32 * 4);
    float* qk1      = (float*)alloc((size_t)NN * 256 * 4);
    float* qk2v     = (float*)alloc((size_t)NN * 32 * 4);
    float* e1       = (float*)alloc((size_t)NE * 8 * 4);
    float* e2       = (float*)alloc((size_t)NE * 4);
    float* h        = (float*)alloc((size_t)NN * DH * 4);
    float* zacc     = (float*)alloc((size_t)NN * DOUT * 4);
    unsigned short* W1Thi = (unsigned short*)alloc((size_t)NR * DH * DIN * 2);
    unsigned short* W1Tlo = (unsigned short*)alloc((size_t)NR * DH * DIN * 2);
    unsigned short* W2Thi = (unsigned short*)alloc((size_t)NR * DOUT * DH * 2);
    unsigned short* W2Tlo = (unsigned short*)alloc((size_t)NR * DOUT * DH * 2);
    unsigned* msgu  = (unsigned*)alloc((size_t)MSGROWS * 256 * 4);  // reused for l2 (64 u32/row)

    hipMemsetAsync(ws, 0, zero_bytes, stream);
    alpha1_kernel<<<DIN, 256, 0, stream>>>(W1, aq1, ak1, alpha1);
    alpha2_kernel<<<(DH * 32 + 255) / 256, 256, 0, stream>>>(W2, aq2, ak2, alpha2);
    splitW1T_kernel<<<NR * 8, 256, 0, stream>>>(W1, W1Thi, W1Tlo);
    splitW2T_kernel<<<NR * 2, 256, 0, stream>>>(W2, W2Thi, W2Tlo);
    hist_kernel<<<(NE + 255) / 256, 256, 0, stream>>>(ei, et, cnt, cnt_d);
    scan_bkt_kernel<<<1, 64, 0, stream>>>(cnt, boffs, cursor, cts);
    tilemap_kernel<<<(NTILESMAX + 255) / 256, 256, 0, stream>>>(boffs, tile_b, tile_s);
    bucket_place_kernel<<<(NE + 255) / 256, 256, 0, stream>>>(ei, et, cursor, border);
    scan_dst_kernel<<<1, 1024, 0, stream>>>(cnt_d, doffs, cursor_d);
    place_dst_kernel<<<(NE + 255) / 256, 256, 0, stream>>>(border, ei, cursor_d, dlist, dedge);
    qk1_kernel<<<(NN + TILE - 1) / TILE, 256, 0, stream>>>(x, alpha1, qk1);
    elogit1_kernel<<<(NE + 255) / 256, 256, 0, stream>>>(ei, et, qk1, e1);
    for (int c = 0; c < CHUNKS; ++c) {
        l1_gemm_kernel<<<MAXTPC, 256, 0, stream>>>(x, W1Thi, W1Tlo, ei, border,
                                                   tile_b, tile_s, boffs, cts, c, msgu);
        l1_agg_kernel<<<CHD, 256, 0, stream>>>(msgu, e1, dlist, dedge, doffs, boffs, c, h);
    }
    qk2_kernel<<<(NN + TILE - 1) / TILE, 256, 0, stream>>>(h, alpha2, qk2v);
    elogit2_kernel<<<(NE + 255) / 256, 256, 0, stream>>>(ei, et, qk2v, e2);
    for (int c = 0; c < CHUNKS; ++c) {
        l2_gemm_kernel<<<MAXTPC, 256, 0, stream>>>(h, W2Thi, W2Tlo, ei, border,
                                                   tile_b, tile_s, boffs, cts, c, msgu);
        l2_agg_kernel<<<(CHD + 3) / 4, 256, 0, stream>>>(msgu, e2, dlist, dedge, doffs, boffs, c, zacc);
    }
    decode_kernel<<<(NT + TILE - 1) / TILE, 256, 0, stream>>>(zacc, tgt, lw1, lb1, lw2, lb2, out);
}

// Round 6
// 1049.886 us; speedup vs baseline: 6.2031x; 1.2875x over previous
//
#include <hip/hip_runtime.h>
#include <cstdint>
#include <cstddef>

#define NN     20000
#define NE     320000
#define NR     16
#define DIN    128
#define DH     512
#define DOUT   128
#define NT     50000
#define TILE   64
#define CHUNKS 8
#define CHD    2500
#define GRP2   4                       // layer-2 chunk grouping
#define NBUCKET (CHUNKS * NR)          // 128
#define MSGROWS 46080                  // max edges per chunk (40000 avg + 32 sigma)
#define MAXTPC  768                    // max GEMM tiles per chunk (l1)
#define MAXTPG  2700                   // max GEMM tiles per group (l2)
#define NTILESMAX (NE / TILE + NBUCKET)

typedef __attribute__((ext_vector_type(8))) short bf16x8;
typedef __attribute__((ext_vector_type(4))) float f32x4;

__device__ __forceinline__ unsigned short f2bf(float x) {
    unsigned int b = __float_as_uint(x);
    b = b + 0x7fffu + ((b >> 16) & 1u);
    return (unsigned short)(b >> 16);
}
__device__ __forceinline__ float bf2f(unsigned short u) {
    return __uint_as_float(((unsigned int)u) << 16);
}
__device__ __forceinline__ unsigned packbf(float lo, float hi) {
    return (unsigned)f2bf(lo) | ((unsigned)f2bf(hi) << 16);
}

// ---------------- fold attention vectors into weights ----------------
__global__ void alpha1_kernel(const float* __restrict__ W1, const float* __restrict__ aq1,
                              const float* __restrict__ ak1, float* __restrict__ alpha1) {
    int i = blockIdx.x;            // 0..127
    int c = threadIdx.x;           // 0..255
    int r = c >> 4, s = (c >> 3) & 1, h = c & 7;
    const float* att = (s == 0 ? aq1 : ak1) + (r * 8 + h) * 64;
    const float* w = W1 + ((size_t)(r * DIN + i)) * DH + h * 64;
    float acc = 0.f;
    #pragma unroll 8
    for (int o = 0; o < 64; ++o) acc += w[o] * att[o];
    alpha1[i * 256 + c] = acc;
}

__global__ void alpha2_kernel(const float* __restrict__ W2, const float* __restrict__ aq2,
                              const float* __restrict__ ak2, float* __restrict__ alpha2) {
    int g = blockIdx.x * blockDim.x + threadIdx.x;
    if (g >= DH * 32) return;
    int i = g >> 5, c = g & 31;
    int r = c >> 1, s = c & 1;
    const float* att = (s == 0 ? aq2 : ak2) + r * DOUT;
    const float* w = W2 + ((size_t)(r * DH + i)) * DOUT;
    float acc = 0.f;
    #pragma unroll 8
    for (int o = 0; o < DOUT; ++o) acc += w[o] * att[o];
    alpha2[i * 32 + c] = acc;
}

// ---------------- bf16 hi/lo precompute ----------------
__global__ void split_x_kernel(const float* __restrict__ x, unsigned short* __restrict__ xhi,
                               unsigned short* __restrict__ xlo) {
    int g = blockIdx.x * 256 + threadIdx.x;
    if (g >= NN * DIN / 4) return;
    float4 v = ((const float4*)x)[g];
    ushort4 h, l;
    h.x = f2bf(v.x); l.x = f2bf(v.x - bf2f(h.x));
    h.y = f2bf(v.y); l.y = f2bf(v.y - bf2f(h.y));
    h.z = f2bf(v.z); l.z = f2bf(v.z - bf2f(h.z));
    h.w = f2bf(v.w); l.w = f2bf(v.w - bf2f(h.w));
    ((ushort4*)xhi)[g] = h;
    ((ushort4*)xlo)[g] = l;
}

// W1 [16][128][512] -> W1T hi/lo [16][512][128]
__global__ void splitW1T_kernel(const float* __restrict__ W1, unsigned short* __restrict__ Whi,
                                unsigned short* __restrict__ Wlo) {
    __shared__ float T[128 * 65];
    int r = blockIdx.x >> 3;
    int ob = blockIdx.x & 7;
    int tid = threadIdx.x;
    for (int idx = tid; idx < 128 * 64; idx += 256) {
        int i = idx >> 6, o = idx & 63;
        T[i * 65 + o] = W1[((size_t)(r * DIN + i)) * DH + ob * 64 + o];
    }
    __syncthreads();
    for (int idx = tid; idx < 64 * 128; idx += 256) {
        int o = idx >> 7, i = idx & 127;
        float v = T[i * 65 + o];
        unsigned short h = f2bf(v);
        size_t off = ((size_t)r * DH + ob * 64 + o) * DIN + i;
        Whi[off] = h;
        Wlo[off] = f2bf(v - bf2f(h));
    }
}

// W2 [16][512][128] -> W2T hi/lo [16][128][512]
__global__ void splitW2T_kernel(const float* __restrict__ W2, unsigned short* __restrict__ Whi,
                                unsigned short* __restrict__ Wlo) {
    __shared__ float T[128 * 65];
    int r = blockIdx.x >> 1;
    int ob = blockIdx.x & 1;
    int tid = threadIdx.x;
    for (int kc = 0; kc < 4; ++kc) {
        if (kc) __syncthreads();
        for (int idx = tid; idx < 128 * 64; idx += 256) {
            int k = idx >> 6, o = idx & 63;
            T[k * 65 + o] = W2[((size_t)(r * DH + kc * 128 + k)) * DOUT + ob * 64 + o];
        }
        __syncthreads();
        for (int idx = tid; idx < 64 * 128; idx += 256) {
            int o = idx >> 7, k = idx & 127;
            float v = T[k * 65 + o];
            unsigned short h = f2bf(v);
            size_t off = ((size_t)r * DOUT + ob * 64 + o) * DH + kc * 128 + k;
            Whi[off] = h;
            Wlo[off] = f2bf(v - bf2f(h));
        }
    }
}

// lw1 [256][128] -> lw1T hi/lo [128][256]
__global__ void splitLw1_kernel(const float* __restrict__ lw1, unsigned short* __restrict__ Lhi,
                                unsigned short* __restrict__ Llo) {
    int g = blockIdx.x * 256 + threadIdx.x;
    if (g >= 256 * 128) return;
    int o = g >> 8, k = g & 255;
    float v = lw1[k * 128 + o];
    unsigned short h = f2bf(v);
    Lhi[(size_t)o * 256 + k] = h;
    Llo[(size_t)o * 256 + k] = f2bf(v - bf2f(h));
}

// ---------------- sorts ----------------
__global__ void hist_kernel(const int* __restrict__ ei, const int* __restrict__ et,
                            int* __restrict__ cnt, int* __restrict__ cnt_d) {
    __shared__ int bins[NBUCKET];
    int t = threadIdx.x;
    if (t < NBUCKET) bins[t] = 0;
    __syncthreads();
    int e = blockIdx.x * 256 + t;
    if (e < NE) {
        int d = ei[NE + e];
        int key = (d / CHD) * NR + et[e];
        atomicAdd(&bins[key], 1);
        atomicAdd(&cnt_d[d], 1);
    }
    __syncthreads();
    if (t < NBUCKET && bins[t]) atomicAdd(&cnt[t], bins[t]);
}

__global__ void scan_bkt_kernel(const int* __restrict__ cnt, int* __restrict__ boffs,
                                int* __restrict__ cursor, int* __restrict__ cts) {
    if (threadIdx.x != 0) return;
    int acc = 0, tiles = 0;
    for (int b = 0; b < NBUCKET; ++b) {
        if ((b & (NR - 1)) == 0) cts[b >> 4] = tiles;
        boffs[b] = acc; cursor[b] = acc;
        int cn = cnt[b];
        tiles += (cn + TILE - 1) / TILE;
        acc += cn;
    }
    boffs[NBUCKET] = acc; cts[CHUNKS] = tiles;
}

__global__ void tilemap_kernel(const int* __restrict__ boffs, int* __restrict__ tile_b,
                               int* __restrict__ tile_s) {
    __shared__ int bo[NBUCKET + 1];
    int tid = threadIdx.x;
    if (tid <= NBUCKET) bo[tid] = boffs[tid];
    __syncthreads();
    int t = blockIdx.x * 256 + tid;
    if (t >= NTILESMAX) return;
    int acc = 0, bb = -1, ss = 0;
    for (int b = 0; b < NBUCKET; ++b) {
        int cn = bo[b + 1] - bo[b];
        int nt = (cn + TILE - 1) / TILE;
        if (t >= acc && t < acc + nt) { bb = b; ss = bo[b] + (t - acc) * TILE; }
        acc += nt;
    }
    tile_b[t] = bb; tile_s[t] = ss;
}

__global__ void bucket_place_kernel(const int* __restrict__ ei, const int* __restrict__ et,
                                    int* __restrict__ cursor, int* __restrict__ border) {
    __shared__ int binc[NBUCKET], base_[NBUCKET], rank_[NBUCKET];
    int t = threadIdx.x;
    if (t < NBUCKET) { binc[t] = 0; rank_[t] = 0; }
    __syncthreads();
    int e = blockIdx.x * 256 + t;
    int key = -1;
    if (e < NE) { key = (ei[NE + e] / CHD) * NR + et[e]; atomicAdd(&binc[key], 1); }
    __syncthreads();
    if (t < NBUCKET && binc[t]) base_[t] = atomicAdd(&cursor[t], binc[t]);
    __syncthreads();
    if (key >= 0) border[base_[key] + atomicAdd(&rank_[key], 1)] = e;
}

__global__ void scan_dst_kernel(const int* __restrict__ cnt_d, int* __restrict__ doffs,
                                int* __restrict__ cursor_d) {
    __shared__ int part[1024];
    int t = threadIdx.x;
    int base = t * 20;
    int s = 0;
    for (int i = 0; i < 20 && base + i < NN; ++i) s += cnt_d[base + i];
    part[t] = s;
    __syncthreads();
    for (int off = 1; off < 1024; off <<= 1) {
        int v = (t >= off) ? part[t - off] : 0;
        __syncthreads();
        part[t] += v;
        __syncthreads();
    }
    int run = part[t] - s;
    for (int i = 0; i < 20 && base + i < NN; ++i) {
        doffs[base + i] = run; cursor_d[base + i] = run;
        run += cnt_d[base + i];
    }
    if (t == 1023) doffs[NN] = part[1023];
}

__global__ void place_dst_kernel(const int* __restrict__ border, const int* __restrict__ ei,
                                 int* __restrict__ cursor_d, int* __restrict__ dlist,
                                 int* __restrict__ dedge) {
    int pos = blockIdx.x * 256 + threadIdx.x;
    if (pos >= NE) return;
    int e = border[pos];
    int d = ei[NE + e];
    int idx = atomicAdd(&cursor_d[d], 1);
    dlist[idx] = pos;
    dedge[idx] = e;
}

// ---------------- qk1 = x @ alpha1  ([N,128] @ [128,256]) ----------------
__global__ void qk1_kernel(const float* __restrict__ x, const float* __restrict__ alpha1,
                           float* __restrict__ qk1) {
    __shared__ float Xt[TILE][DIN + 1];
    int n0 = blockIdx.x * TILE;
    int tid = threadIdx.x;
    for (int idx = tid; idx < TILE * DIN; idx += 256) {
        int row = idx >> 7, i = idx & 127;
        int n = n0 + row;
        Xt[row][i] = (n < NN) ? x[(size_t)n * DIN + i] : 0.f;
    }
    __syncthreads();
    int to = tid >> 4, te = tid & 15;
    for (int c = 0; c < 2; ++c) {
        float acc[4][8] = {};
        const float* Wp = alpha1 + c * 128 + to * 8;
        for (int i = 0; i < DIN; ++i) {
            float4 w0 = *(const float4*)(Wp + (size_t)i * 256);
            float4 w1 = *(const float4*)(Wp + (size_t)i * 256 + 4);
            float w[8] = {w0.x, w0.y, w0.z, w0.w, w1.x, w1.y, w1.z, w1.w};
            #pragma unroll
            for (int a = 0; a < 4; ++a) {
                float xv = Xt[te * 4 + a][i];
                #pragma unroll
                for (int b = 0; b < 8; ++b) acc[a][b] += xv * w[b];
            }
        }
        #pragma unroll
        for (int a = 0; a < 4; ++a) {
            int n = n0 + te * 4 + a;
            if (n < NN) {
                float* op = qk1 + (size_t)n * 256 + c * 128 + to * 8;
                #pragma unroll
                for (int b = 0; b < 8; ++b) op[b] = acc[a][b];
            }
        }
    }
}

__global__ void elogit1_kernel(const int* __restrict__ ei, const int* __restrict__ et,
                               const float* __restrict__ qk1, float* __restrict__ e1) {
    int e = blockIdx.x * blockDim.x + threadIdx.x;
    if (e >= NE) return;
    int src = ei[e], dst = ei[NE + e], r = et[e];
    const float* qp = qk1 + (size_t)dst * 256 + r * 16;
    const float* kp = qk1 + (size_t)src * 256 + r * 16 + 8;
    float* ep = e1 + (size_t)e * 8;
    #pragma unroll
    for (int h = 0; h < 8; ++h) {
        float l = qp[h] + kp[h];
        l = l > 0.f ? l : 0.2f * l;
        ep[h] = __expf(l);
    }
}

// ---------------- layer1 GEMM (MFMA, split bf16): msg (packed bf16) ----------------
__global__ __launch_bounds__(256, 2)
void l1_gemm_kernel(const unsigned short* __restrict__ xhi, const unsigned short* __restrict__ xlo,
                    const unsigned short* __restrict__ W1Thi, const unsigned short* __restrict__ W1Tlo,
                    const int* __restrict__ ei, const int* __restrict__ border,
                    const int* __restrict__ tile_b, const int* __restrict__ tile_s,
                    const int* __restrict__ boffs, const int* __restrict__ cts,
                    int c, unsigned* __restrict__ msgu) {
    int t = cts[c] + blockIdx.x;
    if (t >= cts[c + 1]) return;
    int b = tile_b[t];
    int r = b & (NR - 1);
    int start = tile_s[t];
    int cstart = boffs[c * NR];
    int cnt = boffs[b + 1] - start; if (cnt > TILE) cnt = TILE;
    __shared__ __align__(16) unsigned short Ah[64 * 128];
    __shared__ __align__(16) unsigned short Al[64 * 128];
    __shared__ int srcS[TILE];
    int tid = threadIdx.x;
    if (tid < TILE) {
        int sv = 0;
        if (tid < cnt) { int e = border[start + tid]; sv = ei[e]; }
        srcS[tid] = sv;
    }
    __syncthreads();
    {
        int row = tid >> 2, seg = tid & 3;
        const uint4* ph = (const uint4*)(xhi + (size_t)srcS[row] * DIN + seg * 32);
        const uint4* pl = (const uint4*)(xlo + (size_t)srcS[row] * DIN + seg * 32);
        unsigned rb = row * 256, sw = (row & 7) << 4;
        #pragma unroll
        for (int i = 0; i < 4; ++i) {
            unsigned off = (rb + seg * 64 + i * 16) ^ sw;
            *(uint4*)((char*)Ah + off) = ph[i];
            *(uint4*)((char*)Al + off) = pl[i];
        }
    }
    __syncthreads();
    int w = tid >> 6, lane = tid & 63;
    int l15 = lane & 15, l4 = lane >> 4;
    const unsigned short* Bh = W1Thi + ((size_t)r * DH + w * 128 + l15) * DIN + l4 * 8;
    const unsigned short* Bl = W1Tlo + ((size_t)r * DH + w * 128 + l15) * DIN + l4 * 8;
    f32x4 acc[4][8];
    #pragma unroll
    for (int m = 0; m < 4; ++m)
        #pragma unroll
        for (int n = 0; n < 8; ++n) acc[m][n] = (f32x4){0.f, 0.f, 0.f, 0.f};
    #pragma unroll
    for (int mg = 0; mg < 2; ++mg) {
        bf16x8 ah[2][4], al[2][4];
        #pragma unroll
        for (int mm = 0; mm < 2; ++mm) {
            int row = (mg * 2 + mm) * 16 + l15;
            unsigned rb = row * 256, sw = (row & 7) << 4;
            #pragma unroll
            for (int k = 0; k < 4; ++k) {
                unsigned off = (rb + k * 64 + l4 * 16) ^ sw;
                ah[mm][k] = *(const bf16x8*)((const char*)Ah + off);
                al[mm][k] = *(const bf16x8*)((const char*)Al + off);
            }
        }
        #pragma unroll
        for (int n = 0; n < 8; ++n) {
            #pragma unroll
            for (int k = 0; k < 4; ++k) {
                bf16x8 bh = *(const bf16x8*)(Bh + (size_t)n * 16 * DIN + k * 32);
                bf16x8 bl = *(const bf16x8*)(Bl + (size_t)n * 16 * DIN + k * 32);
                #pragma unroll
                for (int mm = 0; mm < 2; ++mm) {
                    int m = mg * 2 + mm;
                    acc[m][n] = __builtin_amdgcn_mfma_f32_16x16x32_bf16(ah[mm][k], bh, acc[m][n], 0, 0, 0);
                    acc[m][n] = __builtin_amdgcn_mfma_f32_16x16x32_bf16(ah[mm][k], bl, acc[m][n], 0, 0, 0);
                    acc[m][n] = __builtin_amdgcn_mfma_f32_16x16x32_bf16(al[mm][k], bh, acc[m][n], 0, 0, 0);
                }
            }
        }
    }
    unsigned* mb = msgu + (size_t)(start - cstart) * 256 + w * 64 + l15;
    #pragma unroll
    for (int m = 0; m < 4; ++m) {
        int row0 = m * 16 + l4 * 4;
        #pragma unroll
        for (int rg = 0; rg < 4; ++rg) {
            int row = row0 + rg;
            if (row < cnt) {
                unsigned* mp = mb + (size_t)row * 256;
                #pragma unroll
                for (int q = 0; q < 4; ++q) {
                    int n0 = ((q >> 1) << 2) | (q & 1);
                    mp[q * 16] = packbf(acc[m][n0][rg], acc[m][n0 + 2][rg]);
                }
            }
        }
    }
}

// ---------------- layer1 agg (fused qk2): block per dst ----------------
__global__ void l1_agg_kernel(const unsigned* __restrict__ msgu, const float* __restrict__ e1,
                              const int* __restrict__ dlist, const int* __restrict__ dedge,
                              const int* __restrict__ doffs, const int* __restrict__ boffs,
                              int c, unsigned short* __restrict__ hhi, unsigned short* __restrict__ hlo,
                              const float* __restrict__ alpha2, float* __restrict__ qk2v) {
    __shared__ float hrow[DH];
    __shared__ float red[32][9];
    int tid = threadIdx.x;
    int d = c * CHD + blockIdx.x;
    int lo_ = doffs[d], hi_ = doffs[d + 1];
    int cstart = boffs[c * NR];
    int head = tid >> 5;
    float a0 = 0.f, a1 = 0.f, se = 0.f;
    for (int p = lo_; p < hi_; ++p) {
        int pos = dlist[p];
        float wgt = e1[(size_t)dedge[p] * 8 + head];
        se += wgt;
        unsigned v = msgu[(size_t)(pos - cstart) * 256 + tid];
        a0 += wgt * bf2f((unsigned short)(v & 0xffff));
        a1 += wgt * bf2f((unsigned short)(v >> 16));
    }
    float inv = 1.f / (se + 1e-16f);
    a0 *= inv; a1 *= inv;
    a0 = a0 > 0.f ? a0 : 0.f;
    a1 = a1 > 0.f ? a1 : 0.f;
    int w = tid >> 6, q = (tid >> 4) & 3, l15 = tid & 15;
    int n0 = ((q >> 1) << 2) | (q & 1);
    int c0 = w * 128 + n0 * 16 + l15;
    hrow[c0] = a0; hrow[c0 + 32] = a1;
    unsigned short h0 = f2bf(a0), h1 = f2bf(a1);
    hhi[(size_t)d * DH + c0] = h0;
    hlo[(size_t)d * DH + c0] = f2bf(a0 - bf2f(h0));
    hhi[(size_t)d * DH + c0 + 32] = h1;
    hlo[(size_t)d * DH + c0 + 32] = f2bf(a1 - bf2f(h1));
    __syncthreads();
    // fused qk2: out[j] = sum_i hrow[i] * alpha2[i*32+j]
    int j = tid & 31, ib = tid >> 5;
    float s = 0.f;
    #pragma unroll 8
    for (int i = ib * 64; i < ib * 64 + 64; ++i) s += hrow[i] * alpha2[(size_t)i * 32 + j];
    red[j][ib] = s;
    __syncthreads();
    if (tid < 32) {
        float t = 0.f;
        #pragma unroll
        for (int g = 0; g < 8; ++g) t += red[tid][g];
        qk2v[(size_t)d * 32 + tid] = t;
    }
}

__global__ void elogit2_kernel(const int* __restrict__ ei, const int* __restrict__ et,
                               const float* __restrict__ qk2, float* __restrict__ e2) {
    int e = blockIdx.x * blockDim.x + threadIdx.x;
    if (e >= NE) return;
    int src = ei[e], dst = ei[NE + e], r = et[e];
    float l = qk2[(size_t)dst * 32 + r * 2] + qk2[(size_t)src * 32 + r * 2 + 1];
    l = l > 0.f ? l : 0.2f * l;
    e2[e] = __expf(l);
}

// ---------------- layer2 GEMM (MFMA, split bf16), grouped chunks ----------------
__global__ __launch_bounds__(256, 2)
void l2_gemm_kernel(const unsigned short* __restrict__ hhi, const unsigned short* __restrict__ hlo,
                    const unsigned short* __restrict__ W2Thi, const unsigned short* __restrict__ W2Tlo,
                    const int* __restrict__ ei, const int* __restrict__ border,
                    const int* __restrict__ tile_b, const int* __restrict__ tile_s,
                    const int* __restrict__ boffs, const int* __restrict__ cts,
                    int c0, unsigned* __restrict__ msgu2) {
    int t = cts[c0] + blockIdx.x;
    if (t >= cts[c0 + GRP2]) return;
    int b = tile_b[t];
    int r = b & (NR - 1);
    int start = tile_s[t];
    int cstart = boffs[c0 * NR];
    int cnt = boffs[b + 1] - start; if (cnt > TILE) cnt = TILE;
    __shared__ __align__(16) unsigned short Ah[64 * 128];
    __shared__ __align__(16) unsigned short Al[64 * 128];
    __shared__ int srcS[TILE];
    int tid = threadIdx.x;
    if (tid < TILE) {
        int sv = 0;
        if (tid < cnt) { int e = border[start + tid]; sv = ei[e]; }
        srcS[tid] = sv;
    }
    __syncthreads();
    int w = tid >> 6, lane = tid & 63;
    int l15 = lane & 15, l4 = lane >> 4;
    const unsigned short* Bh = W2Thi + ((size_t)r * DOUT + w * 32 + l15) * DH + l4 * 8;
    const unsigned short* Bl = W2Tlo + ((size_t)r * DOUT + w * 32 + l15) * DH + l4 * 8;
    f32x4 acc[4][2];
    #pragma unroll
    for (int m = 0; m < 4; ++m) { acc[m][0] = (f32x4){0.f,0.f,0.f,0.f}; acc[m][1] = (f32x4){0.f,0.f,0.f,0.f}; }
    for (int kc = 0; kc < 4; ++kc) {
        if (kc) __syncthreads();
        {
            int row = tid >> 2, seg = tid & 3;
            const uint4* ph = (const uint4*)(hhi + (size_t)srcS[row] * DH + kc * 128 + seg * 32);
            const uint4* pl = (const uint4*)(hlo + (size_t)srcS[row] * DH + kc * 128 + seg * 32);
            unsigned rb = row * 256, sw = (row & 7) << 4;
            #pragma unroll
            for (int i = 0; i < 4; ++i) {
                unsigned off = (rb + seg * 64 + i * 16) ^ sw;
                *(uint4*)((char*)Ah + off) = ph[i];
                *(uint4*)((char*)Al + off) = pl[i];
            }
        }
        __syncthreads();
        bf16x8 ah[4][4], al[4][4];
        #pragma unroll
        for (int m = 0; m < 4; ++m) {
            int row = m * 16 + l15;
            unsigned rb = row * 256, sw = (row & 7) << 4;
            #pragma unroll
            for (int k = 0; k < 4; ++k) {
                unsigned off = (rb + k * 64 + l4 * 16) ^ sw;
                ah[m][k] = *(const bf16x8*)((const char*)Ah + off);
                al[m][k] = *(const bf16x8*)((const char*)Al + off);
            }
        }
        #pragma unroll
        for (int n = 0; n < 2; ++n) {
            #pragma unroll
            for (int k = 0; k < 4; ++k) {
                bf16x8 bh = *(const bf16x8*)(Bh + (size_t)n * 16 * DH + kc * 128 + k * 32);
                bf16x8 bl = *(const bf16x8*)(Bl + (size_t)n * 16 * DH + kc * 128 + k * 32);
                #pragma unroll
                for (int m = 0; m < 4; ++m) {
                    acc[m][n] = __builtin_amdgcn_mfma_f32_16x16x32_bf16(ah[m][k], bh, acc[m][n], 0, 0, 0);
                    acc[m][n] = __builtin_amdgcn_mfma_f32_16x16x32_bf16(ah[m][k], bl, acc[m][n], 0, 0, 0);
                    acc[m][n] = __builtin_amdgcn_mfma_f32_16x16x32_bf16(al[m][k], bh, acc[m][n], 0, 0, 0);
                }
            }
        }
    }
    unsigned* mb = msgu2 + (size_t)(start - cstart) * 64 + w * 16 + l15;
    #pragma unroll
    for (int m = 0; m < 4; ++m) {
        int row0 = m * 16 + l4 * 4;
        #pragma unroll
        for (int rg = 0; rg < 4; ++rg) {
            int row = row0 + rg;
            if (row < cnt) {
                mb[(size_t)row * 64] = packbf(acc[m][0][rg], acc[m][1][rg]);
            }
        }
    }
}

// ---------------- layer2 agg (grouped): 4 dsts per block, 1 wave per dst ----------------
__global__ void l2_agg_kernel(const unsigned* __restrict__ msgu2, const float* __restrict__ e2,
                              const int* __restrict__ dlist, const int* __restrict__ dedge,
                              const int* __restrict__ doffs, const int* __restrict__ boffs,
                              int c0, float* __restrict__ zacc) {
    int tid = threadIdx.x;
    int dl = blockIdx.x * 4 + (tid >> 6);
    int d = c0 * CHD + dl;
    if (d >= NN) return;
    int slot = tid & 63;
    int lo_ = doffs[d], hi_ = doffs[d + 1];
    int cstart = boffs[c0 * NR];
    float a0 = 0.f, a1 = 0.f, se = 0.f;
    for (int p = lo_; p < hi_; ++p) {
        float wgt = e2[dedge[p]];
        se += wgt;
        unsigned v = msgu2[(size_t)(dlist[p] - cstart) * 64 + slot];
        a0 += wgt * bf2f((unsigned short)(v & 0xffff));
        a1 += wgt * bf2f((unsigned short)(v >> 16));
    }
    float inv = 1.f / (se + 1e-16f);
    int w = slot >> 4, l15 = slot & 15;
    int c0l = w * 32 + l15;
    zacc[(size_t)d * DOUT + c0l] = a0 * inv;
    zacc[(size_t)d * DOUT + c0l + 16] = a1 * inv;
}

// ---------------- link-prediction decoder (MFMA, split bf16) ----------------
__global__ __launch_bounds__(256, 2)
void decode_kernel(const float* __restrict__ z, const int* __restrict__ tgt,
                   const unsigned short* __restrict__ Lhi, const unsigned short* __restrict__ Llo,
                   const float* __restrict__ lb1, const float* __restrict__ lw2,
                   const float* __restrict__ lb2, float* __restrict__ out) {
    __shared__ __align__(16) unsigned short Ah[64 * 256];
    __shared__ __align__(16) unsigned short Al[64 * 256];
    __shared__ float red[TILE][5];
    int t0 = blockIdx.x * TILE;
    int tid = threadIdx.x;
    int cnt = NT - t0; if (cnt > TILE) cnt = TILE;
    {
        int row = tid >> 2, seg = tid & 3;
        int node = 0;
        bool live = (row < cnt);
        if (live) node = tgt[(seg >> 1) * NT + t0 + row];
        const float4* pz = (const float4*)(z + (size_t)node * DOUT + (seg & 1) * 64);
        unsigned rb = row * 512, sb = (seg >> 1) * 256 + (seg & 1) * 128;
        unsigned sw = (row & 7) << 4;
        #pragma unroll
        for (int g = 0; g < 8; ++g) {           // FIX: 8 iterations cover all 64 values/seg
            float4 a = live ? pz[g * 2] : (float4){0,0,0,0};
            float4 bq = live ? pz[g * 2 + 1] : (float4){0,0,0,0};
            unsigned short h0 = f2bf(a.x), h1 = f2bf(a.y), h2 = f2bf(a.z), h3 = f2bf(a.w);
            unsigned short h4 = f2bf(bq.x), h5 = f2bf(bq.y), h6 = f2bf(bq.z), h7 = f2bf(bq.w);
            uint4 uh, ul;
            uh.x = (unsigned)h0 | ((unsigned)h1 << 16);
            uh.y = (unsigned)h2 | ((unsigned)h3 << 16);
            uh.z = (unsigned)h4 | ((unsigned)h5 << 16);
            uh.w = (unsigned)h6 | ((unsigned)h7 << 16);
            ul.x = (unsigned)f2bf(a.x - bf2f(h0)) | ((unsigned)f2bf(a.y - bf2f(h1)) << 16);
            ul.y = (unsigned)f2bf(a.z - bf2f(h2)) | ((unsigned)f2bf(a.w - bf2f(h3)) << 16);
            ul.z = (unsigned)f2bf(bq.x - bf2f(h4)) | ((unsigned)f2bf(bq.y - bf2f(h5)) << 16);
            ul.w = (unsigned)f2bf(bq.z - bf2f(h6)) | ((unsigned)f2bf(bq.w - bf2f(h7)) << 16);
            unsigned off = (rb + sb + g * 16) ^ sw;
            *(uint4*)((char*)Ah + off) = uh;
            *(uint4*)((char*)Al + off) = ul;
        }
    }
    __syncthreads();
    int w = tid >> 6, lane = tid & 63;
    int l15 = lane & 15, l4 = lane >> 4;
    const unsigned short* Bh = Lhi + (size_t)(w * 32 + l15) * 256 + l4 * 8;
    const unsigned short* Bl = Llo + (size_t)(w * 32 + l15) * 256 + l4 * 8;
    f32x4 acc[4][2];
    #pragma unroll
    for (int m = 0; m < 4; ++m) { acc[m][0] = (f32x4){0.f,0.f,0.f,0.f}; acc[m][1] = (f32x4){0.f,0.f,0.f,0.f}; }
    #pragma unroll
    for (int k = 0; k < 8; ++k) {
        bf16x8 ah[4], al[4];
        #pragma unroll
        for (int m = 0; m < 4; ++m) {
            int row = m * 16 + l15;
            unsigned off = ((unsigned)row * 512 + k * 64 + l4 * 16) ^ ((unsigned)(row & 7) << 4);
            ah[m] = *(const bf16x8*)((const char*)Ah + off);
            al[m] = *(const bf16x8*)((const char*)Al + off);
        }
        #pragma unroll
        for (int n = 0; n < 2; ++n) {
            bf16x8 bh = *(const bf16x8*)(Bh + (size_t)n * 16 * 256 + k * 32);
            bf16x8 bl = *(const bf16x8*)(Bl + (size_t)n * 16 * 256 + k * 32);
            #pragma unroll
            for (int m = 0; m < 4; ++m) {
                acc[m][n] = __builtin_amdgcn_mfma_f32_16x16x32_bf16(ah[m], bh, acc[m][n], 0, 0, 0);
                acc[m][n] = __builtin_amdgcn_mfma_f32_16x16x32_bf16(ah[m], bl, acc[m][n], 0, 0, 0);
                acc[m][n] = __builtin_amdgcn_mfma_f32_16x16x32_bf16(al[m], bh, acc[m][n], 0, 0, 0);
            }
        }
    }
    int col0 = w * 32 + l15;
    float lb_0 = lb1[col0], lb_1 = lb1[col0 + 16];
    float lwa = lw2[col0], lwb = lw2[col0 + 16];
    #pragma unroll
    for (int m = 0; m < 4; ++m) {
        #pragma unroll
        for (int rg = 0; rg < 4; ++rg) {
            float h0 = acc[m][0][rg] + lb_0; h0 = h0 > 0.f ? h0 : 0.f;
            float h1 = acc[m][1][rg] + lb_1; h1 = h1 > 0.f ? h1 : 0.f;
            float s = h0 * lwa + h1 * lwb;
            s += __shfl_xor(s, 1); s += __shfl_xor(s, 2);
            s += __shfl_xor(s, 4); s += __shfl_xor(s, 8);
            if (l15 == 0) red[m * 16 + l4 * 4 + rg][w] = s;
        }
    }
    __syncthreads();
    if (tid < cnt) out[t0 + tid] = red[tid][0] + red[tid][1] + red[tid][2] + red[tid][3] + lb2[0];
}

extern "C" void kernel_launch(void* const* d_in, const int* in_sizes, int n_in,
                              void* d_out, int out_size, void* d_ws, size_t ws_size,
                              hipStream_t stream) {
    const float* x   = (const float*)d_in[0];
    const int*   ei  = (const int*)d_in[1];
    const int*   et  = (const int*)d_in[2];
    const int*   tgt = (const int*)d_in[3];
    const float* W1  = (const float*)d_in[4];
    const float* aq1 = (const float*)d_in[5];
    const float* ak1 = (const float*)d_in[6];
    const float* W2  = (const float*)d_in[7];
    const float* aq2 = (const float*)d_in[8];
    const float* ak2 = (const float*)d_in[9];
    const float* lw1 = (const float*)d_in[10];
    const float* lb1 = (const float*)d_in[11];
    const float* lw2 = (const float*)d_in[12];
    const float* lb2 = (const float*)d_in[13];
    float* out = (float*)d_out;
    (void)in_sizes; (void)n_in; (void)out_size; (void)ws_size;

    char* ws = (char*)d_ws;
    size_t off = 0;
    auto alloc = [&](size_t bytes) -> void* {
        void* p = ws + off;
        off += (bytes + 255) & ~(size_t)255;
        return p;
    };
    // zero-init block: histograms only
    int* cnt   = (int*)alloc(NBUCKET * sizeof(int));
    int* cnt_d = (int*)alloc((size_t)NN * sizeof(int));
    size_t zero_bytes = off;
    // no-init scratch
    int*   boffs    = (int*)alloc((NBUCKET + 1) * sizeof(int));
    int*   cursor   = (int*)alloc(NBUCKET * sizeof(int));
    int*   cts      = (int*)alloc((CHUNKS + 1) * sizeof(int));
    int*   doffs    = (int*)alloc((size_t)(NN + 1) * sizeof(int));
    int*   cursor_d = (int*)alloc((size_t)NN * sizeof(int));
    int*   border   = (int*)alloc((size_t)NE * sizeof(int));
    int*   dlist    = (int*)alloc((size_t)NE * sizeof(int));
    int*   dedge    = (int*)alloc((size_t)NE * sizeof(int));
    int*   tile_b   = (int*)alloc((size_t)NTILESMAX * sizeof(int));
    int*   tile_s   = (int*)alloc((size_t)NTILESMAX * sizeof(int));
    float* alpha1   = (float*)alloc((size_t)128 * 256 * 4);
    float* alpha2   = (float*)alloc((size_t)512 * 32 * 4);
    float* qk1      = (float*)alloc((size_t)NN * 256 * 4);
    float* qk2v     = (float*)alloc((size_t)NN * 32 * 4);
    float* e1       = (float*)alloc((size_t)NE * 8 * 4);
    float* e2       = (float*)alloc((size_t)NE * 4);
    float* zacc     = (float*)alloc((size_t)NN * DOUT * 4);
    unsigned short* xhi   = (unsigned short*)alloc((size_t)NN * DIN * 2);
    unsigned short* xlo   = (unsigned short*)alloc((size_t)NN * DIN * 2);
    unsigned short* hhi   = (unsigned short*)alloc((size_t)NN * DH * 2);
    unsigned short* hlo   = (unsigned short*)alloc((size_t)NN * DH * 2);
    unsigned short* W1Thi = (unsigned short*)alloc((size_t)NR * DH * DIN * 2);
    unsigned short* W1Tlo = (unsigned short*)alloc((size_t)NR * DH * DIN * 2);
    unsigned short* W2Thi = (unsigned short*)alloc((size_t)NR * DOUT * DH * 2);
    unsigned short* W2Tlo = (unsigned short*)alloc((size_t)NR * DOUT * DH * 2);
    unsigned short* Lhi   = (unsigned short*)alloc((size_t)128 * 256 * 2);
    unsigned short* Llo   = (unsigned short*)alloc((size_t)128 * 256 * 2);
    unsigned* msgu  = (unsigned*)alloc((size_t)MSGROWS * 256 * 4);  // 47 MB; l2 groups use 64 u32/row

    hipMemsetAsync(ws, 0, zero_bytes, stream);
    alpha1_kernel<<<DIN, 256, 0, stream>>>(W1, aq1, ak1, alpha1);
    alpha2_kernel<<<(DH * 32 + 255) / 256, 256, 0, stream>>>(W2, aq2, ak2, alpha2);
    split_x_kernel<<<(NN * DIN / 4 + 255) / 256, 256, 0, stream>>>(x, xhi, xlo);
    splitW1T_kernel<<<NR * 8, 256, 0, stream>>>(W1, W1Thi, W1Tlo);
    splitW2T_kernel<<<NR * 2, 256, 0, stream>>>(W2, W2Thi, W2Tlo);
    splitLw1_kernel<<<(256 * 128 + 255) / 256, 256, 0, stream>>>(lw1, Lhi, Llo);
    hist_kernel<<<(NE + 255) / 256, 256, 0, stream>>>(ei, et, cnt, cnt_d);
    scan_bkt_kernel<<<1, 64, 0, stream>>>(cnt, boffs, cursor, cts);
    tilemap_kernel<<<(NTILESMAX + 255) / 256, 256, 0, stream>>>(boffs, tile_b, tile_s);
    bucket_place_kernel<<<(NE + 255) / 256, 256, 0, stream>>>(ei, et, cursor, border);
    scan_dst_kernel<<<1, 1024, 0, stream>>>(cnt_d, doffs, cursor_d);
    place_dst_kernel<<<(NE + 255) / 256, 256, 0, stream>>>(border, ei, cursor_d, dlist, dedge);
    qk1_kernel<<<(NN + TILE - 1) / TILE, 256, 0, stream>>>(x, alpha1, qk1);
    elogit1_kernel<<<(NE + 255) / 256, 256, 0, stream>>>(ei, et, qk1, e1);
    for (int c = 0; c < CHUNKS; ++c) {
        l1_gemm_kernel<<<MAXTPC, 256, 0, stream>>>(xhi, xlo, W1Thi, W1Tlo, ei, border,
                                                   tile_b, tile_s, boffs, cts, c, msgu);
        l1_agg_kernel<<<CHD, 256, 0, stream>>>(msgu, e1, dlist, dedge, doffs, boffs, c,
                                               hhi, hlo, alpha2, qk2v);
    }
    elogit2_kernel<<<(NE + 255) / 256, 256, 0, stream>>>(ei, et, qk2v, e2);
    for (int c0 = 0; c0 < CHUNKS; c0 += GRP2) {
        l2_gemm_kernel<<<MAXTPG, 256, 0, stream>>>(hhi, hlo, W2Thi, W2Tlo, ei, border,
                                                   tile_b, tile_s, boffs, cts, c0, msgu);
        l2_agg_kernel<<<(GRP2 * CHD + 3) / 4, 256, 0, stream>>>(msgu, e2, dlist, dedge,
                                                                doffs, boffs, c0, zacc);
    }
    decode_kernel<<<(NT + TILE - 1) / TILE, 256, 0, stream>>>(zacc, tgt, Lhi, Llo,
                                                              lb1, lw2, lb2, out);
}